// Round 5
// baseline (326.649 us; speedup 1.0000x reference)
//
#include <hip/hip_runtime.h>
#include <hip/hip_bf16.h>
#include <cstdint>
#include <cstddef>

typedef unsigned short ushort_t;
typedef __attribute__((ext_vector_type(8))) short short8;     // 8 bf16 = 4 VGPRs (MFMA A/B frag)
typedef __attribute__((ext_vector_type(8))) unsigned short ushort8;
typedef __attribute__((ext_vector_type(4))) unsigned short ushort4v;
typedef __attribute__((ext_vector_type(4))) float f32x4;
typedef __attribute__((ext_vector_type(2))) unsigned long long ull2;
typedef __attribute__((ext_vector_type(2))) unsigned int uint2v;

// Problem constants: B=2, L=2048, DIM=1024, H=16, dk=64
#define LPAD 72   // flash P LDS row stride (u16)

// Counted-vmcnt pipeline barrier (T4): waits own older staging loads (keep N
// newest in flight), closes the ds window (lgkmcnt 0), then raw s_barrier.
#define PIPE_WAIT_BAR(N) do {                                              \
    asm volatile("s_waitcnt vmcnt(" #N ") lgkmcnt(0)" ::: "memory");       \
    __builtin_amdgcn_s_barrier();                                          \
    asm volatile("" ::: "memory");                                         \
} while (0)

__device__ __forceinline__ unsigned short f2bf(float f) {
    unsigned int x = __float_as_uint(f);
    unsigned int r = x + 0x7fffu + ((x >> 16) & 1u);   // RNE
    return (unsigned short)(r >> 16);
}

__device__ __forceinline__ unsigned int cvt_pk_bf16(float lo, float hi) {
    unsigned int r;
    asm("v_cvt_pk_bf16_f32 %0, %1, %2" : "=v"(r) : "v"(lo), "v"(hi));
    return r;
}

// async global->LDS, 16 B per lane. LDS dest = wave-uniform base + lane*16 (m104 caveat).
__device__ __forceinline__ void async16(const ushort_t* g, ushort_t* l) {
    __builtin_amdgcn_global_load_lds(
        (const __attribute__((address_space(1))) unsigned int*)g,
        (__attribute__((address_space(3))) unsigned int*)l,
        16, 0, 0);
}

// Merged prep kernel (1-D range decode):
//   [0, 4096)      : maskbits  — pack mask rows into tile-major bit array
//   [4096, 5632)   : W cvt     — Wq/Wk/Wv fp32 -> bf16 (512 blocks each)
//   [5632, 6656)   : woswz     — Wo fp32 -> bf16, k = h*64+d swizzled ordering
__global__ __launch_bounds__(256) void prep(const int* __restrict__ mask,
                                            const float* __restrict__ Wq,
                                            const float* __restrict__ Wk,
                                            const float* __restrict__ Wv,
                                            const float* __restrict__ Wo,
                                            ushort_t* __restrict__ Wqb,
                                            ushort_t* __restrict__ Wkb,
                                            ushort_t* __restrict__ Wvb,
                                            ushort_t* __restrict__ WoH,
                                            unsigned long long* __restrict__ Mbits) {
    __shared__ float srow[1024 + 64];
    const int bid = blockIdx.x;
    const int tid = threadIdx.x;
    if (bid < 4096) {
        // maskbits: Mbits[(o/64)*4096 + row] bit (o%64), row = b*2048 + i
        const int row  = bid;
        const int w    = tid >> 6;
        const int lane = tid & 63;
        const int* mrow = mask + (size_t)row * 2048;
        #pragma unroll
        for (int it = 0; it < 8; it++) {
            const int o = (it << 8) + (w << 6) + lane;
            const unsigned long long bb = __ballot(mrow[o] != 0);
            if (lane == 0) Mbits[(size_t)((it << 2) + w) * 4096 + row] = bb;
        }
    } else if (bid < 5632) {
        // W cvt: 3 x 1048576 fp32 -> bf16
        const int q    = bid - 4096;
        const int wsel = q >> 9;                 // 0..2
        const float* W = (wsel == 0) ? Wq : (wsel == 1) ? Wk : Wv;
        ushort_t* Wb   = (wsel == 0) ? Wqb : (wsel == 1) ? Wkb : Wvb;
        const size_t idx = (((size_t)(q & 511) << 8) + tid) << 3;
        f32x4 a0 = *(const f32x4*)(W + idx), a1 = *(const f32x4*)(W + idx + 4);
        ushort8 o;
        #pragma unroll
        for (int j = 0; j < 4; j++) { o[j] = f2bf(a0[j]); o[j + 4] = f2bf(a1[j]); }
        *(ushort8*)(Wb + idx) = o;
    } else {
        // woswz: WoH[j][k] = bf16(Wo[j][(k&63)*16 + (k>>6)]), k = h*64+d ordering
        const int j = bid - 5632;
        f32x4 v = *(const f32x4*)(Wo + (size_t)j * 1024 + (tid << 2));
        #pragma unroll
        for (int s = 0; s < 4; s++) { const int c = (tid << 2) + s; srow[c + (c >> 4)] = v[s]; }
        __syncthreads();
        #pragma unroll
        for (int s = 0; s < 4; s++) {
            const int k = tid + (s << 8);
            const int col = ((k & 63) << 4) + (k >> 6);
            WoH[(size_t)j * 1024 + k] = f2bf(srow[col + (col >> 4)]);
        }
    }
}

// Fused QKV projection, 128x128 tile, BK=32, with FUSED fp32->bf16 X conversion
// (T14 issue-early/write-late reg-staging: X(t+1) fp32 loaded into regs at step
// start, converted + ds_write after the MFMAs; X double-buffered). W stays on
// triple-buffered global_load_lds with counted vmcnt(2). The X-consume wait
// implicitly also drains W(t+1) (older in queue) -> pipeline invariant holds.
// 1-D grid 768, decoded so all 8 n-blocks of (z,m) share one XCD.
// z=0: Qh[bh][l][d] (q pre-scaled 1/8); z=1: Kh[bh][l][d]; z=2: VhT[bh][d][l].
__global__ __launch_bounds__(256) void gemm_proj(const float* __restrict__ qf,
                                                 const float* __restrict__ kf,
                                                 const float* __restrict__ vf,
                                                 const ushort_t* __restrict__ Wqb,
                                                 const ushort_t* __restrict__ Wkb,
                                                 const ushort_t* __restrict__ Wvb,
                                                 ushort_t* __restrict__ Qh,
                                                 ushort_t* __restrict__ Kh,
                                                 ushort_t* __restrict__ VhT) {
    __shared__ ushort_t Xs[2][4096];   // 2 x 8 KB: [c4][128 rows][8], reg-staged
    __shared__ ushort_t Ws[3][4096];   // 3 x 8 KB: async16-staged

    const int lid  = blockIdx.x;       // 0..767
    const int nIdx = lid / 96;         // 0..7
    const int rem  = lid % 96;
    const int z    = rem >> 5;         // 0..2
    const int mIdx = rem & 31;         // 0..31
    const int n0   = nIdx << 7;
    const int m0   = mIdx << 7;

    const float* Xf = (z == 0) ? qf : (z == 1) ? kf : vf;
    const ushort_t* Wb = (z == 0) ? Wqb : (z == 1) ? Wkb : Wvb;
    const float sc = (z == 0) ? 0.125f : 1.0f;   // 1/sqrt(dk), exact

    const int tid  = threadIdx.x;
    const int w    = tid >> 6;
    const int lane = tid & 63;
    const int lm   = lane & 15;
    const int quad = lane >> 4;
    const int wm   = w & 1;            // M half
    const int wn   = w >> 1;           // N half

    f32x4 acc[4][4];
    #pragma unroll
    for (int i = 0; i < 4; i++)
        #pragma unroll
        for (int j = 0; j < 4; j++) acc[i][j] = (f32x4){0.f, 0.f, 0.f, 0.f};

    // X chunk decomposition: wave w owns c4=w; chunk i covers rows i*64+lane.
    // LDS index L = w*128 + i*64 + lane (identical layout to async16 version).
    const float* xbase = Xf + (size_t)(m0 + lane) * 1024 + (w << 3);

    auto loadX = [&](int k0, f32x4 xr[2][2]) {
        #pragma unroll
        for (int i = 0; i < 2; i++) {
            const float* sp = xbase + (size_t)(i << 6) * 1024 + k0;
            xr[i][0] = *(const f32x4*)sp;
            xr[i][1] = *(const f32x4*)(sp + 4);
        }
    };
    auto writeX = [&](const f32x4 xr[2][2], int buf) {
        #pragma unroll
        for (int i = 0; i < 2; i++) {
            ushort8 o;
            #pragma unroll
            for (int j = 0; j < 4; j++) {
                o[j]     = f2bf(xr[i][0][j] * sc);
                o[j + 4] = f2bf(xr[i][1][j] * sc);
            }
            const int L = (w << 7) + (i << 6) + lane;
            *(ushort8*)&Xs[buf][L << 3] = o;
        }
    };
    auto stageW = [&](int k0, int buf) {
        #pragma unroll
        for (int i = 0; i < 2; i++) {
            const int L  = (((w << 1) + i) << 6) + lane;   // 0..511
            const int c4 = L >> 7, row = L & 127;
            const int lb = (((w << 1) + i) << 6) << 3;     // wave-uniform LDS base (u16)
            async16(Wb + (size_t)(n0 + row) * 1024 + k0 + (c4 << 3), &Ws[buf][lb]);
        }
    };

    // prologue: X0 regs -> convert -> LDS; W0, W1 async in flight
    {
        f32x4 x0[2][2];
        loadX(0, x0);
        stageW(0, 0);
        stageW(32, 1);
        writeX(x0, 0);                 // consume waits X0 (leaves W0,W1 flying)
        PIPE_WAIT_BAR(2);              // W0 done; W1 in flight
    }

    int wcur = 0;
    for (int t = 0; t < 32; ++t) {
        f32x4 xr[2][2];
        if (t < 31) loadX((t + 1) << 5, xr);            // issue early
        if (t < 30) { int nb = wcur + 2; if (nb >= 3) nb -= 3; stageW((t + 2) << 5, nb); }

        short8 af[4], bf4[4];
        #pragma unroll
        for (int mf = 0; mf < 4; mf++)
            af[mf] = *(const short8*)&Xs[t & 1][((quad << 7) + (wm << 6) + (mf << 4) + lm) << 3];
        #pragma unroll
        for (int nf = 0; nf < 4; nf++)
            bf4[nf] = *(const short8*)&Ws[wcur][((quad << 7) + (wn << 6) + (nf << 4) + lm) << 3];
        #pragma unroll
        for (int mf = 0; mf < 4; mf++)
            #pragma unroll
            for (int nf = 0; nf < 4; nf++)
                acc[mf][nf] = __builtin_amdgcn_mfma_f32_16x16x32_bf16(af[mf], bf4[nf], acc[mf][nf], 0, 0, 0);

        if (t < 31) writeX(xr, (t + 1) & 1);            // convert + write late
        if (t < 30)       PIPE_WAIT_BAR(2);             // W(t+1) done; W(t+2) flying
        else if (t == 30) PIPE_WAIT_BAR(0);
        wcur += 1; if (wcur == 3) wcur = 0;
    }

    // Direct stores. col = n0 + wn*64 + nf*16 + lm -> h = lm, d = 8*nIdx + 4*wn + nf.
    const int bb    = m0 >> 11;
    const int l0    = m0 & 2047;
    const int dbase = (n0 >> 4) + (wn << 2);
    if (z != 2) {
        ushort_t* OUT = (z == 0) ? Qh : Kh;
        #pragma unroll
        for (int mf = 0; mf < 4; mf++)
            #pragma unroll
            for (int r = 0; r < 4; r++) {
                const int row = (wm << 6) + (mf << 4) + (quad << 2) + r;
                ushort4v o = { f2bf(acc[mf][0][r]), f2bf(acc[mf][1][r]),
                               f2bf(acc[mf][2][r]), f2bf(acc[mf][3][r]) };
                *(ushort4v*)(OUT + ((size_t)((bb << 4) + lm) * 2048 + l0 + row) * 64 + dbase) = o;
            }
    } else {
        #pragma unroll
        for (int mf = 0; mf < 4; mf++)
            #pragma unroll
            for (int nf = 0; nf < 4; nf++) {
                const int lbase = l0 + (wm << 6) + (mf << 4) + (quad << 2);
                ushort4v o = { f2bf(acc[mf][nf][0]), f2bf(acc[mf][nf][1]),
                               f2bf(acc[mf][nf][2]), f2bf(acc[mf][nf][3]) };
                *(ushort4v*)(VhT + ((size_t)((bb << 4) + lm) * 64 + dbase + nf) * 2048 + lbase) = o;
            }
    }
}

// Output GEMM, 128x64 tile, BK=32, triple-buffered counted-vmcnt staging
// (3 loads/wave/step -> vmcnt(3)), 512 blocks. XCD-grouped m-panels.
__global__ __launch_bounds__(256) void gemm_out(const ushort_t* __restrict__ mhaH,
                                                const ushort_t* __restrict__ WoH,
                                                float* __restrict__ C) {
    __shared__ ushort_t Xs[3][4096];   // [c4][128 rows][8] 3 x 8KB
    __shared__ ushort_t Ws[3][2048];   // [c4][64 rows][8] 3 x 4KB

    const int lid  = blockIdx.x;       // 0..511
    const int mIdx = ((lid & 7) << 2) | ((lid >> 3) & 3);   // 0..31
    const int nIdx = lid >> 5;                               // 0..15
    const int m0   = mIdx << 7;
    const int n0   = nIdx << 6;

    const int tid  = threadIdx.x;
    const int w    = tid >> 6;
    const int lane = tid & 63;
    const int lm   = lane & 15;
    const int quad = lane >> 4;
    const int wm   = w & 1;            // M half (64 rows)
    const int wn   = w >> 1;           // N half (32 cols)
    const int ab   = m0 >> 11;
    const int al0  = m0 & 2047;

    f32x4 acc[4][2];
    #pragma unroll
    for (int i = 0; i < 4; i++)
        #pragma unroll
        for (int j = 0; j < 2; j++) acc[i][j] = (f32x4){0.f, 0.f, 0.f, 0.f};

    auto stage = [&](int k0, int buf) {
        const int h  = k0 >> 6;
        const int d0 = k0 & 63;
        #pragma unroll
        for (int i = 0; i < 2; i++) {
            const int L   = (i << 8) + (w << 6) + lane;     // 0..511
            const int c4  = L >> 7, row = L & 127;
            async16(mhaH + ((size_t)(ab * 16 + h) * 2048 + al0 + row) * 64 + d0 + (c4 << 3),
                    &Xs[buf][((i << 8) + (w << 6)) << 3]);
        }
        {
            const int L   = (w << 6) + lane;                // 0..255
            const int c4  = L >> 6, row = L & 63;
            async16(WoH + (size_t)(n0 + row) * 1024 + k0 + (c4 << 3),
                    &Ws[buf][(w << 6) << 3]);
        }
    };

    stage(0, 0);
    stage(32, 1);
    PIPE_WAIT_BAR(3);

    int cur = 0;
    for (int t = 0; t < 32; ++t) {
        int nb = cur + 2; if (nb >= 3) nb -= 3;
        if (t < 30) stage((t + 2) << 5, nb);
        short8 af[4], bf2[2];
        #pragma unroll
        for (int mf = 0; mf < 4; mf++)
            af[mf] = *(const short8*)&Xs[cur][((quad << 7) + (wm << 6) + (mf << 4) + lm) << 3];
        #pragma unroll
        for (int nf = 0; nf < 2; nf++)
            bf2[nf] = *(const short8*)&Ws[cur][((quad << 6) + (wn << 5) + (nf << 4) + lm) << 3];
        #pragma unroll
        for (int mf = 0; mf < 4; mf++)
            #pragma unroll
            for (int nf = 0; nf < 2; nf++)
                acc[mf][nf] = __builtin_amdgcn_mfma_f32_16x16x32_bf16(af[mf], bf2[nf], acc[mf][nf], 0, 0, 0);
        if (t < 30)       PIPE_WAIT_BAR(3);
        else if (t == 30) PIPE_WAIT_BAR(0);
        cur += 1; if (cur == 3) cur = 0;
    }
    #pragma unroll
    for (int mf = 0; mf < 4; mf++)
        #pragma unroll
        for (int nf = 0; nf < 2; nf++)
            #pragma unroll
            for (int r = 0; r < 4; r++) {
                const int row = m0 + (wm << 6) + (mf << 4) + (quad << 2) + r;
                const int col = n0 + (wn << 5) + (nf << 4) + lm;
                C[(size_t)row * 1024 + col] = acc[mf][nf][r];
            }
}

// MFMA flash attention v7: triple-buffered counted-vmcnt K/V staging (one
// barrier/tile, prefetch never drained), fragment-order LDS (conflict-free
// lane-linear frag reads), interleaved key map (packed softmax: nibble mask
// + 2x v_cvt_pk_bf16_f32 + one b64 P-write per q-row), per-g Pw buffers
// (no g0-read vs g1-write WAR), setprio(1) around MFMA clusters (T5).
// Grid 512 1-D, XCD-grouped bh (K+V+Q+mask ~3.5MB per XCD L2).
__global__ __launch_bounds__(256, 2) void flash_attn(const ushort_t* __restrict__ Qh,
                                                     const ushort_t* __restrict__ Kh,
                                                     const ushort_t* __restrict__ VhT,
                                                     const unsigned long long* __restrict__ Mbits,
                                                     ushort_t* __restrict__ mhaH) {
    __shared__ ushort_t Ks[3][4096];            // 3 x 8KB fragment-order K tile
    __shared__ ushort_t Vs[3][4096];            // 3 x 8KB fragment-order V^T tile
    __shared__ ushort_t Pw[4][2][16 * LPAD];    // per-wave per-g P [qrow16][key64]

    const int tid  = threadIdx.x;
    const int w    = tid >> 6;
    const int lane = tid & 63;
    const int lm   = lane & 15;
    const int quad = lane >> 4;
    const int lid  = blockIdx.x;             // 0..511
    const int bh   = ((lid & 7) << 2) | ((lid >> 3) & 3);   // 0..31, XCD-grouped
    const int q0   = (lid >> 5) << 7;        // 0..1920
    const int b    = bh >> 4;

    const ushort_t* Qb  = Qh  + ((size_t)bh << 17);
    const ushort_t* Kb  = Kh  + ((size_t)bh << 17);
    const ushort_t* Vtb = VhT + ((size_t)bh << 17);   // [d][l]

    short8 aq[2][2];
    #pragma unroll
    for (int g = 0; g < 2; g++) {
        const ushort_t* qp = Qb + (size_t)(q0 + (w << 5) + (g << 4) + lm) * 64 + (quad << 3);
        aq[g][0] = *(const short8*)qp;
        aq[g][1] = *(const short8*)(qp + 32);
    }

    float l_part[2][4] = {{0.f,0.f,0.f,0.f},{0.f,0.f,0.f,0.f}};
    f32x4 o_acc[2][4] = {{{0.f,0.f,0.f,0.f},{0.f,0.f,0.f,0.f},{0.f,0.f,0.f,0.f},{0.f,0.f,0.f,0.f}},
                         {{0.f,0.f,0.f,0.f},{0.f,0.f,0.f,0.f},{0.f,0.f,0.f,0.f},{0.f,0.f,0.f,0.f}}};

    const int rowbase  = (b << 11) + q0 + (w << 5);
    const int shamt    = (lm & 7) << 2;
    const bool hi_half = lm >= 8;

    const ushort_t* ksrc = Kb  + (size_t)((lm << 2) + w) * 64 + (quad << 3);
    const ushort_t* vsrc = Vtb + (size_t)((w << 4) + lm) * 2048 + (quad << 3);

    auto stageKV = [&](int kt0, int buf) {
        async16(ksrc + (size_t)kt0 * 64,      &Ks[buf][((w << 7)     ) << 3]);
        async16(ksrc + (size_t)kt0 * 64 + 32, &Ks[buf][((w << 7) + 64) << 3]);
        async16(vsrc + kt0,      &Vs[buf][((w << 7)     ) << 3]);
        async16(vsrc + kt0 + 32, &Vs[buf][((w << 7) + 64) << 3]);
    };

    stageKV(0, 0);
    stageKV(64, 1);
    PIPE_WAIT_BAR(4);

    int cur = 0;
    for (int t = 0; t < 32; ++t) {
        const int kt0 = t << 6;
        int nb = cur + 2; if (nb >= 3) nb -= 3;

        // mask words FIRST (older than stage loads -> their auto-wait leaves
        // the prefetch in flight)
        const unsigned long long* Mt = Mbits + (size_t)(kt0 >> 6) * 4096 + rowbase;
        unsigned long long mb[2][4];
        #pragma unroll
        for (int g = 0; g < 2; g++) {
            const unsigned long long* mp = Mt + (g << 4) + (quad << 2);
            ull2 t0 = *(const ull2*)mp;
            ull2 t1 = *(const ull2*)(mp + 2);
            mb[g][0] = t0[0]; mb[g][1] = t0[1]; mb[g][2] = t1[0]; mb[g][3] = t1[1];
        }

        if (t < 30) stageKV(kt0 + 128, nb);   // depth-2 prefetch

        // fragment reads: lane-linear, conflict-free
        short8 bk[4][2], bv[4][2];
        #pragma unroll
        for (int c = 0; c < 4; c++) {
            bk[c][0] = *(const short8*)&Ks[cur][((c << 7) + lane) << 3];
            bk[c][1] = *(const short8*)&Ks[cur][((c << 7) + 64 + lane) << 3];
            bv[c][0] = *(const short8*)&Vs[cur][((c << 7) + lane) << 3];
            bv[c][1] = *(const short8*)&Vs[cur][((c << 7) + 64 + lane) << 3];
        }

        // QK^T both g (S col lm of block c <-> key 4*lm + c)
        f32x4 s[2][4];
        __builtin_amdgcn_s_setprio(1);
        #pragma unroll
        for (int g = 0; g < 2; g++)
            #pragma unroll
            for (int c = 0; c < 4; c++) {
                f32x4 zz = {0.f, 0.f, 0.f, 0.f};
                zz = __builtin_amdgcn_mfma_f32_16x16x32_bf16(aq[g][0], bk[c][0], zz, 0, 0, 0);
                zz = __builtin_amdgcn_mfma_f32_16x16x32_bf16(aq[g][1], bk[c][1], zz, 0, 0, 0);
                s[g][c] = zz;
            }
        __builtin_amdgcn_s_setprio(0);

        // softmax + packed P-write, g0 then g1 (independent buffers)
        #pragma unroll
        for (int g = 0; g < 2; g++) {
            #pragma unroll
            for (int r = 0; r < 4; r++) {
                const unsigned long long m64 = mb[g][r];
                const unsigned word = hi_half ? (unsigned)(m64 >> 32) : (unsigned)m64;
                const unsigned nib  = (word >> shamt) & 0xFu;   // bits for keys 4lm..4lm+3
                float p0 = __expf(s[g][0][r]); if (nib & 1u) p0 = 0.f;
                float p1 = __expf(s[g][1][r]); if (nib & 2u) p1 = 0.f;
                float p2 = __expf(s[g][2][r]); if (nib & 4u) p2 = 0.f;
                float p3 = __expf(s[g][3][r]); if (nib & 8u) p3 = 0.f;
                l_part[g][r] += (p0 + p1) + (p2 + p3);
                uint2v pv2;
                pv2[0] = cvt_pk_bf16(p0, p1);
                pv2[1] = cvt_pk_bf16(p2, p3);
                *(uint2v*)&Pw[w][g][((quad << 2) + r) * LPAD + (lm << 2)] = pv2;
            }
        }

        // P reads + PV, g0 then g1 (g1's softmax above hides g0's LDS latency)
        __builtin_amdgcn_s_setprio(1);
        #pragma unroll
        for (int g = 0; g < 2; g++) {
            short8 ap0 = *(const short8*)&Pw[w][g][lm * LPAD + (quad << 3)];
            short8 ap1 = *(const short8*)&Pw[w][g][lm * LPAD + 32 + (quad << 3)];
            #pragma unroll
            for (int cd = 0; cd < 4; cd++) {
                o_acc[g][cd] = __builtin_amdgcn_mfma_f32_16x16x32_bf16(ap0, bv[cd][0], o_acc[g][cd], 0, 0, 0);
                o_acc[g][cd] = __builtin_amdgcn_mfma_f32_16x16x32_bf16(ap1, bv[cd][1], o_acc[g][cd], 0, 0, 0);
            }
        }
        __builtin_amdgcn_s_setprio(0);

        if (t < 30)       PIPE_WAIT_BAR(4);   // t+1 staged; t+2 in flight
        else if (t == 30) PIPE_WAIT_BAR(0);
        cur += 1; if (cur == 3) cur = 0;
    }

    #pragma unroll
    for (int g = 0; g < 2; g++) {
        #pragma unroll
        for (int r = 0; r < 4; r++) {
            float l = l_part[g][r];
            l += __shfl_xor(l, 1, 64);
            l += __shfl_xor(l, 2, 64);
            l += __shfl_xor(l, 4, 64);
            l += __shfl_xor(l, 8, 64);
            const float inv_l = 1.0f / l;
            const int i = q0 + (w << 5) + (g << 4) + (quad << 2) + r;
            ushort_t* orow = mhaH + (((size_t)bh * 2048 + i) << 6);
            #pragma unroll
            for (int cd = 0; cd < 4; cd++)
                orow[(cd << 4) + lm] = f2bf(o_acc[g][cd][r] * inv_l);
        }
    }
}

extern "C" void kernel_launch(void* const* d_in, const int* in_sizes, int n_in,
                              void* d_out, int out_size, void* d_ws, size_t ws_size,
                              hipStream_t stream) {
    const float* q    = (const float*)d_in[0];
    const float* k    = (const float*)d_in[1];
    const float* v    = (const float*)d_in[2];
    const int*   mask = (const int*)d_in[3];
    const float* Wq   = (const float*)d_in[4];
    const float* Wk   = (const float*)d_in[5];
    const float* Wv   = (const float*)d_in[6];
    const float* Wo   = (const float*)d_in[7];
    float* out = (float*)d_out;

    // ws plan (u16 units): Wqb Wkb Wvb WoH (4M) | Mbits (0.5M) | Qh Kh VhT mhaH (16M)
    // total ~21M u16 = 43 MB.
    ushort_t* Wqb  = (ushort_t*)d_ws;
    ushort_t* Wkb  = Wqb + 1048576;
    ushort_t* Wvb  = Wkb + 1048576;
    ushort_t* WoH  = Wvb + 1048576;
    unsigned long long* Mbits = (unsigned long long*)(WoH + 1048576);
    ushort_t* Qh   = WoH + 1048576 + 524288;
    ushort_t* Kh   = Qh  + 4194304;
    ushort_t* VhT  = Kh  + 4194304;
    ushort_t* mhaH = VhT + 4194304;

    dim3 gb(256);
    prep<<<dim3(6656), gb, 0, stream>>>(mask, Wq, Wk, Wv, Wo, Wqb, Wkb, Wvb, WoH, Mbits);
    gemm_proj<<<dim3(768), gb, 0, stream>>>(q, k, v, Wqb, Wkb, Wvb, Qh, Kh, VhT);
    flash_attn<<<dim3(512), gb, 0, stream>>>(Qh, Kh, VhT, Mbits, mhaH);
    gemm_out<<<dim3(512), gb, 0, stream>>>(mhaH, WoH, out);
}

// Round 7
// 303.809 us; speedup vs baseline: 1.0752x; 1.0752x over previous
//
#include <hip/hip_runtime.h>
#include <hip/hip_bf16.h>
#include <cstdint>
#include <cstddef>

typedef unsigned short ushort_t;
typedef __attribute__((ext_vector_type(8))) short short8;     // 8 bf16 = 4 VGPRs (MFMA A/B frag)
typedef __attribute__((ext_vector_type(8))) unsigned short ushort8;
typedef __attribute__((ext_vector_type(4))) unsigned short ushort4v;
typedef __attribute__((ext_vector_type(4))) float f32x4;
typedef __attribute__((ext_vector_type(2))) unsigned long long ull2;
typedef __attribute__((ext_vector_type(2))) unsigned int uint2v;

// Problem constants: B=2, L=2048, DIM=1024, H=16, dk=64
#define LPAD 72   // flash P LDS row stride (u16)

// Counted-vmcnt pipeline barrier (T4): waits own older staging loads (keep N
// newest in flight), closes the ds window (lgkmcnt 0), then raw s_barrier.
#define PIPE_WAIT_BAR(N) do {                                              \
    asm volatile("s_waitcnt vmcnt(" #N ") lgkmcnt(0)" ::: "memory");       \
    __builtin_amdgcn_s_barrier();                                          \
    asm volatile("" ::: "memory");                                         \
} while (0)

__device__ __forceinline__ unsigned short f2bf(float f) {
    unsigned int x = __float_as_uint(f);
    unsigned int r = x + 0x7fffu + ((x >> 16) & 1u);   // RNE
    return (unsigned short)(r >> 16);
}

__device__ __forceinline__ unsigned int cvt_pk_bf16(float lo, float hi) {
    unsigned int r;
    asm("v_cvt_pk_bf16_f32 %0, %1, %2" : "=v"(r) : "v"(lo), "v"(hi));
    return r;
}

// async global->LDS, 16 B per lane. LDS dest = wave-uniform base + lane*16 (m104 caveat).
__device__ __forceinline__ void async16(const ushort_t* g, ushort_t* l) {
    __builtin_amdgcn_global_load_lds(
        (const __attribute__((address_space(1))) unsigned int*)g,
        (__attribute__((address_space(3))) unsigned int*)l,
        16, 0, 0);
}

// prep1 (1-D range decode): [0,6144) X cvt (z = bid>>11, q scaled 1/8);
// [6144,7680) W cvt (Wq/Wk/Wv fp32 -> bf16).
__global__ __launch_bounds__(256) void prep1(const float* __restrict__ q,
                                             const float* __restrict__ k,
                                             const float* __restrict__ v,
                                             const float* __restrict__ Wq,
                                             const float* __restrict__ Wk,
                                             const float* __restrict__ Wv,
                                             ushort_t* __restrict__ qb,
                                             ushort_t* __restrict__ kb,
                                             ushort_t* __restrict__ vb,
                                             ushort_t* __restrict__ Wqb,
                                             ushort_t* __restrict__ Wkb,
                                             ushort_t* __restrict__ Wvb) {
    const int bid = blockIdx.x;
    const int tid = threadIdx.x;
    const float* src; ushort_t* dst; float sc = 1.0f;
    if (bid < 6144) {
        const int z   = bid >> 11;
        const int blk = bid & 2047;
        const size_t idx = (((size_t)blk << 8) + tid) << 3;
        src = ((z == 0) ? q : (z == 1) ? k : v) + idx;
        dst = ((z == 0) ? qb : (z == 1) ? kb : vb) + idx;
        if (z == 0) sc = 0.125f;
    } else {
        const int qq   = bid - 6144;
        const int wsel = qq >> 9;
        const size_t idx = (((size_t)(qq & 511) << 8) + tid) << 3;
        src = ((wsel == 0) ? Wq : (wsel == 1) ? Wk : Wv) + idx;
        dst = ((wsel == 0) ? Wqb : (wsel == 1) ? Wkb : Wvb) + idx;
    }
    f32x4 a0 = *(const f32x4*)src, a1 = *(const f32x4*)(src + 4);
    ushort8 o;
    #pragma unroll
    for (int j = 0; j < 4; j++) { o[j] = f2bf(a0[j] * sc); o[j + 4] = f2bf(a1[j] * sc); }
    *(ushort8*)dst = o;
}

// prep2 (runs after gemm_proj; WoH/Mbits alias kb which is then dead):
// [0,4096) maskbits; [4096,5120) woswz.
__global__ __launch_bounds__(256) void prep2(const int* __restrict__ mask,
                                             const float* __restrict__ Wo,
                                             ushort_t* __restrict__ WoH,
                                             unsigned long long* __restrict__ Mbits) {
    __shared__ float srow[1024 + 64];
    const int bid = blockIdx.x;
    const int tid = threadIdx.x;
    if (bid < 4096) {
        const int row  = bid;
        const int w    = tid >> 6;
        const int lane = tid & 63;
        const int* mrow = mask + (size_t)row * 2048;
        #pragma unroll
        for (int it = 0; it < 8; it++) {
            const int o = (it << 8) + (w << 6) + lane;
            const unsigned long long bb = __ballot(mrow[o] != 0);
            if (lane == 0) Mbits[(size_t)((it << 2) + w) * 4096 + row] = bb;
        }
    } else {
        const int j = bid - 4096;
        f32x4 v = *(const f32x4*)(Wo + (size_t)j * 1024 + (tid << 2));
        #pragma unroll
        for (int s = 0; s < 4; s++) { const int c = (tid << 2) + s; srow[c + (c >> 4)] = v[s]; }
        __syncthreads();
        #pragma unroll
        for (int s = 0; s < 4; s++) {
            const int k = tid + (s << 8);
            const int col = ((k & 63) << 4) + (k >> 6);
            WoH[(size_t)j * 1024 + k] = f2bf(srow[col + (col >> 4)]);
        }
    }
}

// Fused QKV projection, 256x256 tile (staged-BW fix: 2x arithmetic intensity vs
// 128x128 -> staged traffic 384->192 MB), BK=32, 512 threads (8 waves, wave-tile
// 128x64, acc 8x4), triple-buffered counted-vmcnt global_load_lds staging.
// Grid 192 (3z x 16m x 4n), decoded so the 4 n-blocks of (z,m) share one XCD.
// z=0: Qh[bh][l][d] (q pre-scaled 1/8); z=1: Kh[bh][l][d]; z=2: VhT[bh][d][l].
__global__ __launch_bounds__(512, 2) void gemm_proj(const ushort_t* __restrict__ qb,
                                                    const ushort_t* __restrict__ kb,
                                                    const ushort_t* __restrict__ vb,
                                                    const ushort_t* __restrict__ Wqb,
                                                    const ushort_t* __restrict__ Wkb,
                                                    const ushort_t* __restrict__ Wvb,
                                                    ushort_t* __restrict__ Qh,
                                                    ushort_t* __restrict__ Kh,
                                                    ushort_t* __restrict__ VhT) {
    __shared__ ushort_t Xs[3][8192];   // 3 x 16 KB: [c4][256 rows][8]
    __shared__ ushort_t Ws[3][8192];   // 3 x 16 KB

    const int lid  = blockIdx.x;       // 0..191
    const int nIdx = lid / 48;         // 0..3
    const int rem  = lid % 48;
    const int z    = rem >> 4;         // 0..2
    const int mIdx = rem & 15;         // 0..15
    const int n0   = nIdx << 8;
    const int m0   = mIdx << 8;

    const ushort_t* Xb = (z == 0) ? qb : (z == 1) ? kb : vb;
    const ushort_t* Wb = (z == 0) ? Wqb : (z == 1) ? Wkb : Wvb;

    const int tid  = threadIdx.x;
    const int w    = tid >> 6;         // 0..7
    const int lane = tid & 63;
    const int lm   = lane & 15;
    const int quad = lane >> 4;
    const int wm   = w & 1;            // M half (128 rows)
    const int wn   = w >> 1;           // N quarter (64 cols)

    f32x4 acc[8][4];
    #pragma unroll
    for (int i = 0; i < 8; i++)
        #pragma unroll
        for (int j = 0; j < 4; j++) acc[i][j] = (f32x4){0.f, 0.f, 0.f, 0.f};

    // staging: 1024 lane-chunks of 16B cover [c4=4][256 rows]; wave w owns
    // chunks L = (w*2+i)*64 + lane, i<2, for X and same for W. LDS linear:
    // index (c4*256+row)*8 = L*8 -> dest is wave-uniform base + lane*16.
    auto stage = [&](int k0, int buf) {
        #pragma unroll
        for (int i = 0; i < 2; i++) {
            const int L   = (((w << 1) + i) << 6) + lane;   // 0..1023
            const int c4  = L >> 8, row = L & 255;
            const int lb  = (((w << 1) + i) << 6) << 3;     // wave-uniform LDS base (u16)
            async16(Xb + (size_t)(m0 + row) * 1024 + k0 + (c4 << 3), &Xs[buf][lb]);
            async16(Wb + (size_t)(n0 + row) * 1024 + k0 + (c4 << 3), &Ws[buf][lb]);
        }
    };

    stage(0, 0);                       // 4 loads/wave
    stage(32, 1);                      // +4 in flight
    PIPE_WAIT_BAR(4);                  // tile 0 ready; tile 1 flying

    int cur = 0;
    for (int t = 0; t < 32; ++t) {
        int nb = cur + 2; if (nb >= 3) nb -= 3;
        if (t < 30) stage((t + 2) << 5, nb);
        short8 af[8], bf4[4];
        #pragma unroll
        for (int mf = 0; mf < 8; mf++)
            af[mf] = *(const short8*)&Xs[cur][((quad << 8) + (wm << 7) + (mf << 4) + lm) << 3];
        #pragma unroll
        for (int nf = 0; nf < 4; nf++)
            bf4[nf] = *(const short8*)&Ws[cur][((quad << 8) + (wn << 6) + (nf << 4) + lm) << 3];
        #pragma unroll
        for (int mf = 0; mf < 8; mf++)
            #pragma unroll
            for (int nf = 0; nf < 4; nf++)
                acc[mf][nf] = __builtin_amdgcn_mfma_f32_16x16x32_bf16(af[mf], bf4[nf], acc[mf][nf], 0, 0, 0);
        if (t < 30)       PIPE_WAIT_BAR(4);   // t+1 done; t+2 in flight
        else if (t == 30) PIPE_WAIT_BAR(0);
        cur += 1; if (cur == 3) cur = 0;
    }

    // Direct stores. col = n0 + wn*64 + nf*16 + lm -> h = lm, d = 16*nIdx + 4*wn + nf.
    const int bb    = m0 >> 11;
    const int l0    = m0 & 2047;
    const int dbase = (n0 >> 4) + (wn << 2);
    if (z != 2) {
        ushort_t* OUT = (z == 0) ? Qh : Kh;
        #pragma unroll
        for (int mf = 0; mf < 8; mf++)
            #pragma unroll
            for (int r = 0; r < 4; r++) {
                const int row = (wm << 7) + (mf << 4) + (quad << 2) + r;
                ushort4v o = { f2bf(acc[mf][0][r]), f2bf(acc[mf][1][r]),
                               f2bf(acc[mf][2][r]), f2bf(acc[mf][3][r]) };
                *(ushort4v*)(OUT + ((size_t)((bb << 4) + lm) * 2048 + l0 + row) * 64 + dbase) = o;
            }
    } else {
        #pragma unroll
        for (int mf = 0; mf < 8; mf++)
            #pragma unroll
            for (int nf = 0; nf < 4; nf++) {
                const int lbase = l0 + (wm << 7) + (mf << 4) + (quad << 2);
                ushort4v o = { f2bf(acc[mf][nf][0]), f2bf(acc[mf][nf][1]),
                               f2bf(acc[mf][nf][2]), f2bf(acc[mf][nf][3]) };
                *(ushort4v*)(VhT + ((size_t)((bb << 4) + lm) * 64 + dbase + nf) * 2048 + lbase) = o;
            }
    }
}

// Output GEMM, 128x64 tile, BK=32, triple-buffered counted-vmcnt staging
// (3 loads/wave/step -> vmcnt(3)), 512 blocks. XCD-grouped m-panels.
__global__ __launch_bounds__(256) void gemm_out(const ushort_t* __restrict__ mhaH,
                                                const ushort_t* __restrict__ WoH,
                                                float* __restrict__ C) {
    __shared__ ushort_t Xs[3][4096];   // [c4][128 rows][8] 3 x 8KB
    __shared__ ushort_t Ws[3][2048];   // [c4][64 rows][8] 3 x 4KB

    const int lid  = blockIdx.x;       // 0..511
    const int mIdx = ((lid & 7) << 2) | ((lid >> 3) & 3);   // 0..31
    const int nIdx = lid >> 5;                               // 0..15
    const int m0   = mIdx << 7;
    const int n0   = nIdx << 6;

    const int tid  = threadIdx.x;
    const int w    = tid >> 6;
    const int lane = tid & 63;
    const int lm   = lane & 15;
    const int quad = lane >> 4;
    const int wm   = w & 1;            // M half (64 rows)
    const int wn   = w >> 1;           // N half (32 cols)
    const int ab   = m0 >> 11;
    const int al0  = m0 & 2047;

    f32x4 acc[4][2];
    #pragma unroll
    for (int i = 0; i < 4; i++)
        #pragma unroll
        for (int j = 0; j < 2; j++) acc[i][j] = (f32x4){0.f, 0.f, 0.f, 0.f};

    auto stage = [&](int k0, int buf) {
        const int h  = k0 >> 6;
        const int d0 = k0 & 63;
        #pragma unroll
        for (int i = 0; i < 2; i++) {
            const int L   = (i << 8) + (w << 6) + lane;     // 0..511
            const int c4  = L >> 7, row = L & 127;
            async16(mhaH + ((size_t)(ab * 16 + h) * 2048 + al0 + row) * 64 + d0 + (c4 << 3),
                    &Xs[buf][((i << 8) + (w << 6)) << 3]);
        }
        {
            const int L   = (w << 6) + lane;                // 0..255
            const int c4  = L >> 6, row = L & 63;
            async16(WoH + (size_t)(n0 + row) * 1024 + k0 + (c4 << 3),
                    &Ws[buf][(w << 6) << 3]);
        }
    };

    stage(0, 0);
    stage(32, 1);
    PIPE_WAIT_BAR(3);

    int cur = 0;
    for (int t = 0; t < 32; ++t) {
        int nb = cur + 2; if (nb >= 3) nb -= 3;
        if (t < 30) stage((t + 2) << 5, nb);
        short8 af[4], bf2[2];
        #pragma unroll
        for (int mf = 0; mf < 4; mf++)
            af[mf] = *(const short8*)&Xs[cur][((quad << 7) + (wm << 6) + (mf << 4) + lm) << 3];
        #pragma unroll
        for (int nf = 0; nf < 2; nf++)
            bf2[nf] = *(const short8*)&Ws[cur][((quad << 6) + (wn << 5) + (nf << 4) + lm) << 3];
        #pragma unroll
        for (int mf = 0; mf < 4; mf++)
            #pragma unroll
            for (int nf = 0; nf < 2; nf++)
                acc[mf][nf] = __builtin_amdgcn_mfma_f32_16x16x32_bf16(af[mf], bf2[nf], acc[mf][nf], 0, 0, 0);
        if (t < 30)       PIPE_WAIT_BAR(3);
        else if (t == 30) PIPE_WAIT_BAR(0);
        cur += 1; if (cur == 3) cur = 0;
    }
    #pragma unroll
    for (int mf = 0; mf < 4; mf++)
        #pragma unroll
        for (int nf = 0; nf < 2; nf++)
            #pragma unroll
            for (int r = 0; r < 4; r++) {
                const int row = m0 + (wm << 6) + (mf << 4) + (quad << 2) + r;
                const int col = n0 + (wn << 5) + (nf << 4) + lm;
                C[(size_t)row * 1024 + col] = acc[mf][nf][r];
            }
}

// MFMA flash attention v7 (round-4 proven): triple-buffered counted-vmcnt K/V
// staging, fragment-order LDS (conflict-free lane-linear frag reads),
// interleaved key map (packed softmax: nibble mask + 2x v_cvt_pk_bf16_f32 +
// one b64 P-write per q-row), per-g Pw buffers, setprio around MFMA clusters.
// Grid 512 1-D, XCD-grouped bh (K+V+Q+mask ~3.5MB per XCD L2).
__global__ __launch_bounds__(256, 2) void flash_attn(const ushort_t* __restrict__ Qh,
                                                     const ushort_t* __restrict__ Kh,
                                                     const ushort_t* __restrict__ VhT,
                                                     const unsigned long long* __restrict__ Mbits,
                                                     ushort_t* __restrict__ mhaH) {
    __shared__ ushort_t Ks[3][4096];            // 3 x 8KB fragment-order K tile
    __shared__ ushort_t Vs[3][4096];            // 3 x 8KB fragment-order V^T tile
    __shared__ ushort_t Pw[4][2][16 * LPAD];    // per-wave per-g P [qrow16][key64]

    const int tid  = threadIdx.x;
    const int w    = tid >> 6;
    const int lane = tid & 63;
    const int lm   = lane & 15;
    const int quad = lane >> 4;
    const int lid  = blockIdx.x;             // 0..511
    const int bh   = ((lid & 7) << 2) | ((lid >> 3) & 3);   // 0..31, XCD-grouped
    const int q0   = (lid >> 5) << 7;        // 0..1920
    const int b    = bh >> 4;

    const ushort_t* Qb  = Qh  + ((size_t)bh << 17);
    const ushort_t* Kb  = Kh  + ((size_t)bh << 17);
    const ushort_t* Vtb = VhT + ((size_t)bh << 17);   // [d][l]

    short8 aq[2][2];
    #pragma unroll
    for (int g = 0; g < 2; g++) {
        const ushort_t* qp = Qb + (size_t)(q0 + (w << 5) + (g << 4) + lm) * 64 + (quad << 3);
        aq[g][0] = *(const short8*)qp;
        aq[g][1] = *(const short8*)(qp + 32);
    }

    float l_part[2][4] = {{0.f,0.f,0.f,0.f},{0.f,0.f,0.f,0.f}};
    f32x4 o_acc[2][4] = {{{0.f,0.f,0.f,0.f},{0.f,0.f,0.f,0.f},{0.f,0.f,0.f,0.f},{0.f,0.f,0.f,0.f}},
                         {{0.f,0.f,0.f,0.f},{0.f,0.f,0.f,0.f},{0.f,0.f,0.f,0.f},{0.f,0.f,0.f,0.f}}};

    const int rowbase  = (b << 11) + q0 + (w << 5);
    const int shamt    = (lm & 7) << 2;
    const bool hi_half = lm >= 8;

    const ushort_t* ksrc = Kb  + (size_t)((lm << 2) + w) * 64 + (quad << 3);
    const ushort_t* vsrc = Vtb + (size_t)((w << 4) + lm) * 2048 + (quad << 3);

    auto stageKV = [&](int kt0, int buf) {
        async16(ksrc + (size_t)kt0 * 64,      &Ks[buf][((w << 7)     ) << 3]);
        async16(ksrc + (size_t)kt0 * 64 + 32, &Ks[buf][((w << 7) + 64) << 3]);
        async16(vsrc + kt0,      &Vs[buf][((w << 7)     ) << 3]);
        async16(vsrc + kt0 + 32, &Vs[buf][((w << 7) + 64) << 3]);
    };

    stageKV(0, 0);
    stageKV(64, 1);
    PIPE_WAIT_BAR(4);

    int cur = 0;
    for (int t = 0; t < 32; ++t) {
        const int kt0 = t << 6;
        int nb = cur + 2; if (nb >= 3) nb -= 3;

        // mask words FIRST (older than stage loads -> their auto-wait leaves
        // the prefetch in flight)
        const unsigned long long* Mt = Mbits + (size_t)(kt0 >> 6) * 4096 + rowbase;
        unsigned long long mb[2][4];
        #pragma unroll
        for (int g = 0; g < 2; g++) {
            const unsigned long long* mp = Mt + (g << 4) + (quad << 2);
            ull2 t0 = *(const ull2*)mp;
            ull2 t1 = *(const ull2*)(mp + 2);
            mb[g][0] = t0[0]; mb[g][1] = t0[1]; mb[g][2] = t1[0]; mb[g][3] = t1[1];
        }

        if (t < 30) stageKV(kt0 + 128, nb);   // depth-2 prefetch

        // fragment reads: lane-linear, conflict-free
        short8 bk[4][2], bv[4][2];
        #pragma unroll
        for (int c = 0; c < 4; c++) {
            bk[c][0] = *(const short8*)&Ks[cur][((c << 7) + lane) << 3];
            bk[c][1] = *(const short8*)&Ks[cur][((c << 7) + 64 + lane) << 3];
            bv[c][0] = *(const short8*)&Vs[cur][((c << 7) + lane) << 3];
            bv[c][1] = *(const short8*)&Vs[cur][((c << 7) + 64 + lane) << 3];
        }

        // QK^T both g (S col lm of block c <-> key 4*lm + c)
        f32x4 s[2][4];
        __builtin_amdgcn_s_setprio(1);
        #pragma unroll
        for (int g = 0; g < 2; g++)
            #pragma unroll
            for (int c = 0; c < 4; c++) {
                f32x4 zz = {0.f, 0.f, 0.f, 0.f};
                zz = __builtin_amdgcn_mfma_f32_16x16x32_bf16(aq[g][0], bk[c][0], zz, 0, 0, 0);
                zz = __builtin_amdgcn_mfma_f32_16x16x32_bf16(aq[g][1], bk[c][1], zz, 0, 0, 0);
                s[g][c] = zz;
            }
        __builtin_amdgcn_s_setprio(0);

        // softmax + packed P-write, g0 then g1 (independent buffers)
        #pragma unroll
        for (int g = 0; g < 2; g++) {
            #pragma unroll
            for (int r = 0; r < 4; r++) {
                const unsigned long long m64 = mb[g][r];
                const unsigned word = hi_half ? (unsigned)(m64 >> 32) : (unsigned)m64;
                const unsigned nib  = (word >> shamt) & 0xFu;   // bits for keys 4lm..4lm+3
                float p0 = __expf(s[g][0][r]); if (nib & 1u) p0 = 0.f;
                float p1 = __expf(s[g][1][r]); if (nib & 2u) p1 = 0.f;
                float p2 = __expf(s[g][2][r]); if (nib & 4u) p2 = 0.f;
                float p3 = __expf(s[g][3][r]); if (nib & 8u) p3 = 0.f;
                l_part[g][r] += (p0 + p1) + (p2 + p3);
                uint2v pv2;
                pv2[0] = cvt_pk_bf16(p0, p1);
                pv2[1] = cvt_pk_bf16(p2, p3);
                *(uint2v*)&Pw[w][g][((quad << 2) + r) * LPAD + (lm << 2)] = pv2;
            }
        }

        // P reads + PV, g0 then g1 (g1's softmax above hides g0's LDS latency)
        __builtin_amdgcn_s_setprio(1);
        #pragma unroll
        for (int g = 0; g < 2; g++) {
            short8 ap0 = *(const short8*)&Pw[w][g][lm * LPAD + (quad << 3)];
            short8 ap1 = *(const short8*)&Pw[w][g][lm * LPAD + 32 + (quad << 3)];
            #pragma unroll
            for (int cd = 0; cd < 4; cd++) {
                o_acc[g][cd] = __builtin_amdgcn_mfma_f32_16x16x32_bf16(ap0, bv[cd][0], o_acc[g][cd], 0, 0, 0);
                o_acc[g][cd] = __builtin_amdgcn_mfma_f32_16x16x32_bf16(ap1, bv[cd][1], o_acc[g][cd], 0, 0, 0);
            }
        }
        __builtin_amdgcn_s_setprio(0);

        if (t < 30)       PIPE_WAIT_BAR(4);   // t+1 staged; t+2 in flight
        else if (t == 30) PIPE_WAIT_BAR(0);
        cur += 1; if (cur == 3) cur = 0;
    }

    #pragma unroll
    for (int g = 0; g < 2; g++) {
        #pragma unroll
        for (int r = 0; r < 4; r++) {
            float l = l_part[g][r];
            l += __shfl_xor(l, 1, 64);
            l += __shfl_xor(l, 2, 64);
            l += __shfl_xor(l, 4, 64);
            l += __shfl_xor(l, 8, 64);
            const float inv_l = 1.0f / l;
            const int i = q0 + (w << 5) + (g << 4) + (quad << 2) + r;
            ushort_t* orow = mhaH + (((size_t)bh * 2048 + i) << 6);
            #pragma unroll
            for (int cd = 0; cd < 4; cd++)
                orow[(cd << 4) + lm] = f2bf(o_acc[g][cd][r] * inv_l);
        }
    }
}

extern "C" void kernel_launch(void* const* d_in, const int* in_sizes, int n_in,
                              void* d_out, int out_size, void* d_ws, size_t ws_size,
                              hipStream_t stream) {
    const float* q    = (const float*)d_in[0];
    const float* k    = (const float*)d_in[1];
    const float* v    = (const float*)d_in[2];
    const int*   mask = (const int*)d_in[3];
    const float* Wq   = (const float*)d_in[4];
    const float* Wk   = (const float*)d_in[5];
    const float* Wv   = (const float*)d_in[6];
    const float* Wo   = (const float*)d_in[7];
    float* out = (float*)d_out;

    // ws plan (u16 units): qb kb vb (4M) | Wqb Wkb Wvb (1M) | Qh Kh VhT (4M) = 27M u16 = 54 MB
    // mhaH aliases qb; WoH + Mbits alias kb (both dead after gemm_proj; prep2
    // writes them AFTER gemm_proj).
    ushort_t* qb   = (ushort_t*)d_ws;
    ushort_t* kb   = qb  + 4194304;
    ushort_t* vb   = kb  + 4194304;
    ushort_t* Wqb  = vb  + 4194304;
    ushort_t* Wkb  = Wqb + 1048576;
    ushort_t* Wvb  = Wkb + 1048576;
    ushort_t* Qh   = Wvb + 1048576;
    ushort_t* Kh   = Qh  + 4194304;
    ushort_t* VhT  = Kh  + 4194304;
    ushort_t* mhaH = qb;
    ushort_t* WoH  = kb;
    unsigned long long* Mbits = (unsigned long long*)(kb + 1048576);

    dim3 gb(256);
    prep1<<<dim3(7680), gb, 0, stream>>>(q, k, v, Wq, Wk, Wv, qb, kb, vb, Wqb, Wkb, Wvb);
    gemm_proj<<<dim3(192), dim3(512), 0, stream>>>(qb, kb, vb, Wqb, Wkb, Wvb, Qh, Kh, VhT);
    prep2<<<dim3(5120), gb, 0, stream>>>(mask, Wo, WoH, Mbits);
    flash_attn<<<dim3(512), gb, 0, stream>>>(Qh, Kh, VhT, Mbits, mhaH);
    gemm_out<<<dim3(512), gb, 0, stream>>>(mhaH, WoH, out);
}

// Round 8
// 292.914 us; speedup vs baseline: 1.1152x; 1.0372x over previous
//
#include <hip/hip_runtime.h>
#include <hip/hip_bf16.h>
#include <cstdint>
#include <cstddef>

typedef unsigned short ushort_t;
typedef __attribute__((ext_vector_type(8))) short short8;     // 8 bf16 = 4 VGPRs (MFMA A/B frag)
typedef __attribute__((ext_vector_type(8))) unsigned short ushort8;
typedef __attribute__((ext_vector_type(4))) unsigned short ushort4v;
typedef __attribute__((ext_vector_type(4))) float f32x4;
typedef __attribute__((ext_vector_type(2))) unsigned long long ull2;
typedef __attribute__((ext_vector_type(2))) unsigned int uint2v;

// Problem constants: B=2, L=2048, DIM=1024, H=16, dk=64
#define LPAD 72   // flash P LDS row stride (u16)

// Counted-vmcnt pipeline barrier (T4): waits own older staging loads (keep N
// newest in flight), closes the ds window (lgkmcnt 0), then raw s_barrier.
#define PIPE_WAIT_BAR(N) do {                                              \
    asm volatile("s_waitcnt vmcnt(" #N ") lgkmcnt(0)" ::: "memory");       \
    __builtin_amdgcn_s_barrier();                                          \
    asm volatile("" ::: "memory");                                         \
} while (0)

__device__ __forceinline__ unsigned short f2bf(float f) {
    unsigned int x = __float_as_uint(f);
    unsigned int r = x + 0x7fffu + ((x >> 16) & 1u);   // RNE
    return (unsigned short)(r >> 16);
}

__device__ __forceinline__ unsigned int cvt_pk_bf16(float lo, float hi) {
    unsigned int r;
    asm("v_cvt_pk_bf16_f32 %0, %1, %2" : "=v"(r) : "v"(lo), "v"(hi));
    return r;
}

// async global->LDS, 16 B per lane. LDS dest = wave-uniform base + lane*16 (m104 caveat).
__device__ __forceinline__ void async16(const ushort_t* g, ushort_t* l) {
    __builtin_amdgcn_global_load_lds(
        (const __attribute__((address_space(1))) unsigned int*)g,
        (__attribute__((address_space(3))) unsigned int*)l,
        16, 0, 0);
}

// prep1 (1-D range decode): [0,6144) X cvt (z = bid>>11, q scaled 1/8);
// [6144,7680) W cvt (Wq/Wk/Wv fp32 -> bf16).
__global__ __launch_bounds__(256) void prep1(const float* __restrict__ q,
                                             const float* __restrict__ k,
                                             const float* __restrict__ v,
                                             const float* __restrict__ Wq,
                                             const float* __restrict__ Wk,
                                             const float* __restrict__ Wv,
                                             ushort_t* __restrict__ qb,
                                             ushort_t* __restrict__ kb,
                                             ushort_t* __restrict__ vb,
                                             ushort_t* __restrict__ Wqb,
                                             ushort_t* __restrict__ Wkb,
                                             ushort_t* __restrict__ Wvb) {
    const int bid = blockIdx.x;
    const int tid = threadIdx.x;
    const float* src; ushort_t* dst; float sc = 1.0f;
    if (bid < 6144) {
        const int z   = bid >> 11;
        const int blk = bid & 2047;
        const size_t idx = (((size_t)blk << 8) + tid) << 3;
        src = ((z == 0) ? q : (z == 1) ? k : v) + idx;
        dst = ((z == 0) ? qb : (z == 1) ? kb : vb) + idx;
        if (z == 0) sc = 0.125f;
    } else {
        const int qq   = bid - 6144;
        const int wsel = qq >> 9;
        const size_t idx = (((size_t)(qq & 511) << 8) + tid) << 3;
        src = ((wsel == 0) ? Wq : (wsel == 1) ? Wk : Wv) + idx;
        dst = ((wsel == 0) ? Wqb : (wsel == 1) ? Wkb : Wvb) + idx;
    }
    f32x4 a0 = *(const f32x4*)src, a1 = *(const f32x4*)(src + 4);
    ushort8 o;
    #pragma unroll
    for (int j = 0; j < 4; j++) { o[j] = f2bf(a0[j] * sc); o[j + 4] = f2bf(a1[j] * sc); }
    *(ushort8*)dst = o;
}

// prep2 (runs after gemm_proj; WoH/Mbits alias kb which is then dead):
// [0,4096) maskbits; [4096,5120) woswz.
__global__ __launch_bounds__(256) void prep2(const int* __restrict__ mask,
                                             const float* __restrict__ Wo,
                                             ushort_t* __restrict__ WoH,
                                             unsigned long long* __restrict__ Mbits) {
    __shared__ float srow[1024 + 64];
    const int bid = blockIdx.x;
    const int tid = threadIdx.x;
    if (bid < 4096) {
        const int row  = bid;
        const int w    = tid >> 6;
        const int lane = tid & 63;
        const int* mrow = mask + (size_t)row * 2048;
        #pragma unroll
        for (int it = 0; it < 8; it++) {
            const int o = (it << 8) + (w << 6) + lane;
            const unsigned long long bb = __ballot(mrow[o] != 0);
            if (lane == 0) Mbits[(size_t)((it << 2) + w) * 4096 + row] = bb;
        }
    } else {
        const int j = bid - 4096;
        f32x4 v = *(const f32x4*)(Wo + (size_t)j * 1024 + (tid << 2));
        #pragma unroll
        for (int s = 0; s < 4; s++) { const int c = (tid << 2) + s; srow[c + (c >> 4)] = v[s]; }
        __syncthreads();
        #pragma unroll
        for (int s = 0; s < 4; s++) {
            const int k = tid + (s << 8);
            const int col = ((k & 63) << 4) + (k >> 6);
            WoH[(size_t)j * 1024 + k] = f2bf(srow[col + (col >> 4)]);
        }
    }
}

// Fused QKV projection, 256x256 tile, BK=32, 512 threads (8 waves, wave-tile
// 128x64, acc 8x4), triple-buffered counted-vmcnt staging + 4-PHASE fine
// interleave (T3 analog of m201's 8-phase at BK=32): per phase
// {frag ds_reads for quadrant || 1 staging async16} -> s_barrier -> setprio(1)
// -> 8-MFMA cluster -> setprio(0) -> s_barrier. Mid-step barriers are
// alignment-only (reads target buf cur, staging writes buf nb); boundary keeps
// the verified vmcnt(4) invariant. Fragment-order LDS: 0 bank conflicts.
// Grid 192 (3z x 16m x 4n), the 4 n-blocks of (z,m) share one XCD.
// z=0: Qh[bh][l][d] (q pre-scaled 1/8); z=1: Kh[bh][l][d]; z=2: VhT[bh][d][l].
__global__ __launch_bounds__(512, 2) void gemm_proj(const ushort_t* __restrict__ qb,
                                                    const ushort_t* __restrict__ kb,
                                                    const ushort_t* __restrict__ vb,
                                                    const ushort_t* __restrict__ Wqb,
                                                    const ushort_t* __restrict__ Wkb,
                                                    const ushort_t* __restrict__ Wvb,
                                                    ushort_t* __restrict__ Qh,
                                                    ushort_t* __restrict__ Kh,
                                                    ushort_t* __restrict__ VhT) {
    __shared__ ushort_t Xs[3][8192];   // 3 x 16 KB: [c4][256 rows][8]
    __shared__ ushort_t Ws[3][8192];   // 3 x 16 KB

    const int lid  = blockIdx.x;       // 0..191
    const int nIdx = lid / 48;         // 0..3
    const int rem  = lid % 48;
    const int z    = rem >> 4;         // 0..2
    const int mIdx = rem & 15;         // 0..15
    const int n0   = nIdx << 8;
    const int m0   = mIdx << 8;

    const ushort_t* Xb = (z == 0) ? qb : (z == 1) ? kb : vb;
    const ushort_t* Wb = (z == 0) ? Wqb : (z == 1) ? Wkb : Wvb;

    const int tid  = threadIdx.x;
    const int w    = tid >> 6;         // 0..7
    const int lane = tid & 63;
    const int lm   = lane & 15;
    const int quad = lane >> 4;
    const int wm   = w & 1;            // M half (128 rows)
    const int wn   = w >> 1;           // N quarter (64 cols)

    f32x4 acc[8][4];
    #pragma unroll
    for (int i = 0; i < 8; i++)
        #pragma unroll
        for (int j = 0; j < 4; j++) acc[i][j] = (f32x4){0.f, 0.f, 0.f, 0.f};

    // staging: 1024 lane-chunks of 16B cover [c4=4][256 rows]; wave w owns
    // chunks L = (w*2+i)*64 + lane, i<2. LDS index L*8 -> wave-uniform + lane*16.
    // stage1(i): one async16 pair-half (X or W selected by caller).
    auto stageX1 = [&](int k0, int buf, int i) {
        const int L   = (((w << 1) + i) << 6) + lane;   // 0..1023
        const int c4  = L >> 8, row = L & 255;
        const int lb  = (((w << 1) + i) << 6) << 3;
        async16(Xb + (size_t)(m0 + row) * 1024 + k0 + (c4 << 3), &Xs[buf][lb]);
    };
    auto stageW1 = [&](int k0, int buf, int i) {
        const int L   = (((w << 1) + i) << 6) + lane;
        const int c4  = L >> 8, row = L & 255;
        const int lb  = (((w << 1) + i) << 6) << 3;
        async16(Wb + (size_t)(n0 + row) * 1024 + k0 + (c4 << 3), &Ws[buf][lb]);
    };
    auto stage = [&](int k0, int buf) {
        stageX1(k0, buf, 0); stageX1(k0, buf, 1);
        stageW1(k0, buf, 0); stageW1(k0, buf, 1);
    };

    stage(0, 0);                       // 4 loads/wave
    stage(32, 1);                      // +4 in flight
    PIPE_WAIT_BAR(4);                  // tile 0 ready; tile 1 flying

    int cur = 0;
    for (int t = 0; t < 32; ++t) {
        int nb = cur + 2; if (nb >= 3) nb -= 3;
        const bool pf  = (t < 30);
        const int  k0n = (t + 2) << 5;
        short8 af[4], bf[4];

        // ---- phase 0: af(mh=0) + bf(nh=0) reads || stage X.i0; MFMA (mh0,nh0)
        #pragma unroll
        for (int mf = 0; mf < 4; mf++)
            af[mf] = *(const short8*)&Xs[cur][((quad << 8) + (wm << 7) + (mf << 4) + lm) << 3];
        bf[0] = *(const short8*)&Ws[cur][((quad << 8) + (wn << 6) + (0 << 4) + lm) << 3];
        bf[1] = *(const short8*)&Ws[cur][((quad << 8) + (wn << 6) + (1 << 4) + lm) << 3];
        if (pf) stageX1(k0n, nb, 0);
        __builtin_amdgcn_s_barrier();
        __builtin_amdgcn_s_setprio(1);
        #pragma unroll
        for (int mf = 0; mf < 4; mf++) {
            acc[mf][0] = __builtin_amdgcn_mfma_f32_16x16x32_bf16(af[mf], bf[0], acc[mf][0], 0, 0, 0);
            acc[mf][1] = __builtin_amdgcn_mfma_f32_16x16x32_bf16(af[mf], bf[1], acc[mf][1], 0, 0, 0);
        }
        __builtin_amdgcn_s_setprio(0);
        __builtin_amdgcn_s_barrier();

        // ---- phase 1: bf(nh=1) reads || stage X.i1; MFMA (mh0,nh1)
        bf[2] = *(const short8*)&Ws[cur][((quad << 8) + (wn << 6) + (2 << 4) + lm) << 3];
        bf[3] = *(const short8*)&Ws[cur][((quad << 8) + (wn << 6) + (3 << 4) + lm) << 3];
        if (pf) stageX1(k0n, nb, 1);
        __builtin_amdgcn_s_barrier();
        __builtin_amdgcn_s_setprio(1);
        #pragma unroll
        for (int mf = 0; mf < 4; mf++) {
            acc[mf][2] = __builtin_amdgcn_mfma_f32_16x16x32_bf16(af[mf], bf[2], acc[mf][2], 0, 0, 0);
            acc[mf][3] = __builtin_amdgcn_mfma_f32_16x16x32_bf16(af[mf], bf[3], acc[mf][3], 0, 0, 0);
        }
        __builtin_amdgcn_s_setprio(0);
        __builtin_amdgcn_s_barrier();

        // ---- phase 2: af(mh=1) reads || stage W.i0; MFMA (mh1,nh0)
        #pragma unroll
        for (int mf = 0; mf < 4; mf++)
            af[mf] = *(const short8*)&Xs[cur][((quad << 8) + (wm << 7) + 64 + (mf << 4) + lm) << 3];
        if (pf) stageW1(k0n, nb, 0);
        __builtin_amdgcn_s_barrier();
        __builtin_amdgcn_s_setprio(1);
        #pragma unroll
        for (int mf = 0; mf < 4; mf++) {
            acc[4 + mf][0] = __builtin_amdgcn_mfma_f32_16x16x32_bf16(af[mf], bf[0], acc[4 + mf][0], 0, 0, 0);
            acc[4 + mf][1] = __builtin_amdgcn_mfma_f32_16x16x32_bf16(af[mf], bf[1], acc[4 + mf][1], 0, 0, 0);
        }
        __builtin_amdgcn_s_setprio(0);
        __builtin_amdgcn_s_barrier();

        // ---- phase 3: stage W.i1; MFMA (mh1,nh1); boundary counted-vmcnt bar
        if (pf) stageW1(k0n, nb, 1);
        __builtin_amdgcn_s_setprio(1);
        #pragma unroll
        for (int mf = 0; mf < 4; mf++) {
            acc[4 + mf][2] = __builtin_amdgcn_mfma_f32_16x16x32_bf16(af[mf], bf[2], acc[4 + mf][2], 0, 0, 0);
            acc[4 + mf][3] = __builtin_amdgcn_mfma_f32_16x16x32_bf16(af[mf], bf[3], acc[4 + mf][3], 0, 0, 0);
        }
        __builtin_amdgcn_s_setprio(0);
        if (t < 30)       PIPE_WAIT_BAR(4);   // t+1 done; t+2 in flight
        else if (t == 30) PIPE_WAIT_BAR(0);   // last tile: drain
        cur += 1; if (cur == 3) cur = 0;
    }

    // Direct stores. col = n0 + wn*64 + nf*16 + lm -> h = lm, d = 16*nIdx + 4*wn + nf.
    const int bb    = m0 >> 11;
    const int l0    = m0 & 2047;
    const int dbase = (n0 >> 4) + (wn << 2);
    if (z != 2) {
        ushort_t* OUT = (z == 0) ? Qh : Kh;
        #pragma unroll
        for (int mf = 0; mf < 8; mf++)
            #pragma unroll
            for (int r = 0; r < 4; r++) {
                const int row = (wm << 7) + (mf << 4) + (quad << 2) + r;
                ushort4v o = { f2bf(acc[mf][0][r]), f2bf(acc[mf][1][r]),
                               f2bf(acc[mf][2][r]), f2bf(acc[mf][3][r]) };
                *(ushort4v*)(OUT + ((size_t)((bb << 4) + lm) * 2048 + l0 + row) * 64 + dbase) = o;
            }
    } else {
        #pragma unroll
        for (int mf = 0; mf < 8; mf++)
            #pragma unroll
            for (int nf = 0; nf < 4; nf++) {
                const int lbase = l0 + (wm << 7) + (mf << 4) + (quad << 2);
                ushort4v o = { f2bf(acc[mf][nf][0]), f2bf(acc[mf][nf][1]),
                               f2bf(acc[mf][nf][2]), f2bf(acc[mf][nf][3]) };
                *(ushort4v*)(VhT + ((size_t)((bb << 4) + lm) * 64 + dbase + nf) * 2048 + lbase) = o;
            }
    }
}

// Output GEMM, 128x64 tile, BK=32, triple-buffered counted-vmcnt staging
// (3 loads/wave/step -> vmcnt(3)), 512 blocks. XCD-grouped m-panels.
__global__ __launch_bounds__(256) void gemm_out(const ushort_t* __restrict__ mhaH,
                                                const ushort_t* __restrict__ WoH,
                                                float* __restrict__ C) {
    __shared__ ushort_t Xs[3][4096];   // [c4][128 rows][8] 3 x 8KB
    __shared__ ushort_t Ws[3][2048];   // [c4][64 rows][8] 3 x 4KB

    const int lid  = blockIdx.x;       // 0..511
    const int mIdx = ((lid & 7) << 2) | ((lid >> 3) & 3);   // 0..31
    const int nIdx = lid >> 5;                               // 0..15
    const int m0   = mIdx << 7;
    const int n0   = nIdx << 6;

    const int tid  = threadIdx.x;
    const int w    = tid >> 6;
    const int lane = tid & 63;
    const int lm   = lane & 15;
    const int quad = lane >> 4;
    const int wm   = w & 1;            // M half (64 rows)
    const int wn   = w >> 1;           // N half (32 cols)
    const int ab   = m0 >> 11;
    const int al0  = m0 & 2047;

    f32x4 acc[4][2];
    #pragma unroll
    for (int i = 0; i < 4; i++)
        #pragma unroll
        for (int j = 0; j < 2; j++) acc[i][j] = (f32x4){0.f, 0.f, 0.f, 0.f};

    auto stage = [&](int k0, int buf) {
        const int h  = k0 >> 6;
        const int d0 = k0 & 63;
        #pragma unroll
        for (int i = 0; i < 2; i++) {
            const int L   = (i << 8) + (w << 6) + lane;     // 0..511
            const int c4  = L >> 7, row = L & 127;
            async16(mhaH + ((size_t)(ab * 16 + h) * 2048 + al0 + row) * 64 + d0 + (c4 << 3),
                    &Xs[buf][((i << 8) + (w << 6)) << 3]);
        }
        {
            const int L   = (w << 6) + lane;                // 0..255
            const int c4  = L >> 6, row = L & 63;
            async16(WoH + (size_t)(n0 + row) * 1024 + k0 + (c4 << 3),
                    &Ws[buf][(w << 6) << 3]);
        }
    };

    stage(0, 0);
    stage(32, 1);
    PIPE_WAIT_BAR(3);

    int cur = 0;
    for (int t = 0; t < 32; ++t) {
        int nb = cur + 2; if (nb >= 3) nb -= 3;
        if (t < 30) stage((t + 2) << 5, nb);
        short8 af[4], bf2[2];
        #pragma unroll
        for (int mf = 0; mf < 4; mf++)
            af[mf] = *(const short8*)&Xs[cur][((quad << 7) + (wm << 6) + (mf << 4) + lm) << 3];
        #pragma unroll
        for (int nf = 0; nf < 2; nf++)
            bf2[nf] = *(const short8*)&Ws[cur][((quad << 6) + (wn << 5) + (nf << 4) + lm) << 3];
        #pragma unroll
        for (int mf = 0; mf < 4; mf++)
            #pragma unroll
            for (int nf = 0; nf < 2; nf++)
                acc[mf][nf] = __builtin_amdgcn_mfma_f32_16x16x32_bf16(af[mf], bf2[nf], acc[mf][nf], 0, 0, 0);
        if (t < 30)       PIPE_WAIT_BAR(3);
        else if (t == 30) PIPE_WAIT_BAR(0);
        cur += 1; if (cur == 3) cur = 0;
    }
    #pragma unroll
    for (int mf = 0; mf < 4; mf++)
        #pragma unroll
        for (int nf = 0; nf < 2; nf++)
            #pragma unroll
            for (int r = 0; r < 4; r++) {
                const int row = m0 + (wm << 6) + (mf << 4) + (quad << 2) + r;
                const int col = n0 + (wn << 5) + (nf << 4) + lm;
                C[(size_t)row * 1024 + col] = acc[mf][nf][r];
            }
}

// MFMA flash attention v7 (round-4 proven): triple-buffered counted-vmcnt K/V
// staging, fragment-order LDS (conflict-free lane-linear frag reads),
// interleaved key map (packed softmax: nibble mask + 2x v_cvt_pk_bf16_f32 +
// one b64 P-write per q-row), per-g Pw buffers, setprio around MFMA clusters.
// Grid 512 1-D, XCD-grouped bh (K+V+Q+mask ~3.5MB per XCD L2).
__global__ __launch_bounds__(256, 2) void flash_attn(const ushort_t* __restrict__ Qh,
                                                     const ushort_t* __restrict__ Kh,
                                                     const ushort_t* __restrict__ VhT,
                                                     const unsigned long long* __restrict__ Mbits,
                                                     ushort_t* __restrict__ mhaH) {
    __shared__ ushort_t Ks[3][4096];            // 3 x 8KB fragment-order K tile
    __shared__ ushort_t Vs[3][4096];            // 3 x 8KB fragment-order V^T tile
    __shared__ ushort_t Pw[4][2][16 * LPAD];    // per-wave per-g P [qrow16][key64]

    const int tid  = threadIdx.x;
    const int w    = tid >> 6;
    const int lane = tid & 63;
    const int lm   = lane & 15;
    const int quad = lane >> 4;
    const int lid  = blockIdx.x;             // 0..511
    const int bh   = ((lid & 7) << 2) | ((lid >> 3) & 3);   // 0..31, XCD-grouped
    const int q0   = (lid >> 5) << 7;        // 0..1920
    const int b    = bh >> 4;

    const ushort_t* Qb  = Qh  + ((size_t)bh << 17);
    const ushort_t* Kb  = Kh  + ((size_t)bh << 17);
    const ushort_t* Vtb = VhT + ((size_t)bh << 17);   // [d][l]

    short8 aq[2][2];
    #pragma unroll
    for (int g = 0; g < 2; g++) {
        const ushort_t* qp = Qb + (size_t)(q0 + (w << 5) + (g << 4) + lm) * 64 + (quad << 3);
        aq[g][0] = *(const short8*)qp;
        aq[g][1] = *(const short8*)(qp + 32);
    }

    float l_part[2][4] = {{0.f,0.f,0.f,0.f},{0.f,0.f,0.f,0.f}};
    f32x4 o_acc[2][4] = {{{0.f,0.f,0.f,0.f},{0.f,0.f,0.f,0.f},{0.f,0.f,0.f,0.f},{0.f,0.f,0.f,0.f}},
                         {{0.f,0.f,0.f,0.f},{0.f,0.f,0.f,0.f},{0.f,0.f,0.f,0.f},{0.f,0.f,0.f,0.f}}};

    const int rowbase  = (b << 11) + q0 + (w << 5);
    const int shamt    = (lm & 7) << 2;
    const bool hi_half = lm >= 8;

    const ushort_t* ksrc = Kb  + (size_t)((lm << 2) + w) * 64 + (quad << 3);
    const ushort_t* vsrc = Vtb + (size_t)((w << 4) + lm) * 2048 + (quad << 3);

    auto stageKV = [&](int kt0, int buf) {
        async16(ksrc + (size_t)kt0 * 64,      &Ks[buf][((w << 7)     ) << 3]);
        async16(ksrc + (size_t)kt0 * 64 + 32, &Ks[buf][((w << 7) + 64) << 3]);
        async16(vsrc + kt0,      &Vs[buf][((w << 7)     ) << 3]);
        async16(vsrc + kt0 + 32, &Vs[buf][((w << 7) + 64) << 3]);
    };

    stageKV(0, 0);
    stageKV(64, 1);
    PIPE_WAIT_BAR(4);

    int cur = 0;
    for (int t = 0; t < 32; ++t) {
        const int kt0 = t << 6;
        int nb = cur + 2; if (nb >= 3) nb -= 3;

        // mask words FIRST (older than stage loads -> their auto-wait leaves
        // the prefetch in flight)
        const unsigned long long* Mt = Mbits + (size_t)(kt0 >> 6) * 4096 + rowbase;
        unsigned long long mb[2][4];
        #pragma unroll
        for (int g = 0; g < 2; g++) {
            const unsigned long long* mp = Mt + (g << 4) + (quad << 2);
            ull2 t0 = *(const ull2*)mp;
            ull2 t1 = *(const ull2*)(mp + 2);
            mb[g][0] = t0[0]; mb[g][1] = t0[1]; mb[g][2] = t1[0]; mb[g][3] = t1[1];
        }

        if (t < 30) stageKV(kt0 + 128, nb);   // depth-2 prefetch

        // fragment reads: lane-linear, conflict-free
        short8 bk[4][2], bv[4][2];
        #pragma unroll
        for (int c = 0; c < 4; c++) {
            bk[c][0] = *(const short8*)&Ks[cur][((c << 7) + lane) << 3];
            bk[c][1] = *(const short8*)&Ks[cur][((c << 7) + 64 + lane) << 3];
            bv[c][0] = *(const short8*)&Vs[cur][((c << 7) + lane) << 3];
            bv[c][1] = *(const short8*)&Vs[cur][((c << 7) + 64 + lane) << 3];
        }

        // QK^T both g (S col lm of block c <-> key 4*lm + c)
        f32x4 s[2][4];
        __builtin_amdgcn_s_setprio(1);
        #pragma unroll
        for (int g = 0; g < 2; g++)
            #pragma unroll
            for (int c = 0; c < 4; c++) {
                f32x4 zz = {0.f, 0.f, 0.f, 0.f};
                zz = __builtin_amdgcn_mfma_f32_16x16x32_bf16(aq[g][0], bk[c][0], zz, 0, 0, 0);
                zz = __builtin_amdgcn_mfma_f32_16x16x32_bf16(aq[g][1], bk[c][1], zz, 0, 0, 0);
                s[g][c] = zz;
            }
        __builtin_amdgcn_s_setprio(0);

        // softmax + packed P-write, g0 then g1 (independent buffers)
        #pragma unroll
        for (int g = 0; g < 2; g++) {
            #pragma unroll
            for (int r = 0; r < 4; r++) {
                const unsigned long long m64 = mb[g][r];
                const unsigned word = hi_half ? (unsigned)(m64 >> 32) : (unsigned)m64;
                const unsigned nib  = (word >> shamt) & 0xFu;   // bits for keys 4lm..4lm+3
                float p0 = __expf(s[g][0][r]); if (nib & 1u) p0 = 0.f;
                float p1 = __expf(s[g][1][r]); if (nib & 2u) p1 = 0.f;
                float p2 = __expf(s[g][2][r]); if (nib & 4u) p2 = 0.f;
                float p3 = __expf(s[g][3][r]); if (nib & 8u) p3 = 0.f;
                l_part[g][r] += (p0 + p1) + (p2 + p3);
                uint2v pv2;
                pv2[0] = cvt_pk_bf16(p0, p1);
                pv2[1] = cvt_pk_bf16(p2, p3);
                *(uint2v*)&Pw[w][g][((quad << 2) + r) * LPAD + (lm << 2)] = pv2;
            }
        }

        // P reads + PV, g0 then g1 (g1's softmax above hides g0's LDS latency)
        __builtin_amdgcn_s_setprio(1);
        #pragma unroll
        for (int g = 0; g < 2; g++) {
            short8 ap0 = *(const short8*)&Pw[w][g][lm * LPAD + (quad << 3)];
            short8 ap1 = *(const short8*)&Pw[w][g][lm * LPAD + 32 + (quad << 3)];
            #pragma unroll
            for (int cd = 0; cd < 4; cd++) {
                o_acc[g][cd] = __builtin_amdgcn_mfma_f32_16x16x32_bf16(ap0, bv[cd][0], o_acc[g][cd], 0, 0, 0);
                o_acc[g][cd] = __builtin_amdgcn_mfma_f32_16x16x32_bf16(ap1, bv[cd][1], o_acc[g][cd], 0, 0, 0);
            }
        }
        __builtin_amdgcn_s_setprio(0);

        if (t < 30)       PIPE_WAIT_BAR(4);   // t+1 staged; t+2 in flight
        else if (t == 30) PIPE_WAIT_BAR(0);
        cur += 1; if (cur == 3) cur = 0;
    }

    #pragma unroll
    for (int g = 0; g < 2; g++) {
        #pragma unroll
        for (int r = 0; r < 4; r++) {
            float l = l_part[g][r];
            l += __shfl_xor(l, 1, 64);
            l += __shfl_xor(l, 2, 64);
            l += __shfl_xor(l, 4, 64);
            l += __shfl_xor(l, 8, 64);
            const float inv_l = 1.0f / l;
            const int i = q0 + (w << 5) + (g << 4) + (quad << 2) + r;
            ushort_t* orow = mhaH + (((size_t)bh * 2048 + i) << 6);
            #pragma unroll
            for (int cd = 0; cd < 4; cd++)
                orow[(cd << 4) + lm] = f2bf(o_acc[g][cd][r] * inv_l);
        }
    }
}

extern "C" void kernel_launch(void* const* d_in, const int* in_sizes, int n_in,
                              void* d_out, int out_size, void* d_ws, size_t ws_size,
                              hipStream_t stream) {
    const float* q    = (const float*)d_in[0];
    const float* k    = (const float*)d_in[1];
    const float* v    = (const float*)d_in[2];
    const int*   mask = (const int*)d_in[3];
    const float* Wq   = (const float*)d_in[4];
    const float* Wk   = (const float*)d_in[5];
    const float* Wv   = (const float*)d_in[6];
    const float* Wo   = (const float*)d_in[7];
    float* out = (float*)d_out;

    // ws plan (u16 units): qb kb vb (4M) | Wqb Wkb Wvb (1M) | Qh Kh VhT (4M) = 27M u16 = 54 MB
    // mhaH aliases qb; WoH + Mbits alias kb (both dead after gemm_proj; prep2
    // writes them AFTER gemm_proj).
    ushort_t* qb   = (ushort_t*)d_ws;
    ushort_t* kb   = qb  + 4194304;
    ushort_t* vb   = kb  + 4194304;
    ushort_t* Wqb  = vb  + 4194304;
    ushort_t* Wkb  = Wqb + 1048576;
    ushort_t* Wvb  = Wkb + 1048576;
    ushort_t* Qh   = Wvb + 1048576;
    ushort_t* Kh   = Qh  + 4194304;
    ushort_t* VhT  = Kh  + 4194304;
    ushort_t* mhaH = qb;
    ushort_t* WoH  = kb;
    unsigned long long* Mbits = (unsigned long long*)(kb + 1048576);

    dim3 gb(256);
    prep1<<<dim3(7680), gb, 0, stream>>>(q, k, v, Wq, Wk, Wv, qb, kb, vb, Wqb, Wkb, Wvb);
    gemm_proj<<<dim3(192), dim3(512), 0, stream>>>(qb, kb, vb, Wqb, Wkb, Wvb, Qh, Kh, VhT);
    prep2<<<dim3(5120), gb, 0, stream>>>(mask, Wo, WoH, Mbits);
    flash_attn<<<dim3(512), gb, 0, stream>>>(Qh, Kh, VhT, Mbits, mhaH);
    gemm_out<<<dim3(512), gb, 0, stream>>>(mhaH, WoH, out);
}

// Round 9
// 290.051 us; speedup vs baseline: 1.1262x; 1.0099x over previous
//
#include <hip/hip_runtime.h>
#include <hip/hip_bf16.h>
#include <cstdint>
#include <cstddef>

typedef unsigned short ushort_t;
typedef __attribute__((ext_vector_type(8))) short short8;     // 8 bf16 = 4 VGPRs (MFMA A/B frag)
typedef __attribute__((ext_vector_type(8))) unsigned short ushort8;
typedef __attribute__((ext_vector_type(4))) unsigned short ushort4v;
typedef __attribute__((ext_vector_type(4))) float f32x4;
typedef __attribute__((ext_vector_type(2))) unsigned long long ull2;
typedef __attribute__((ext_vector_type(2))) unsigned int uint2v;

// Problem constants: B=2, L=2048, DIM=1024, H=16, dk=64
#define LPAD 72   // flash P LDS row stride (u16)

// Counted-vmcnt pipeline barrier (T4): waits own older staging loads (keep N
// newest in flight), closes the ds window (lgkmcnt 0), then raw s_barrier.
#define PIPE_WAIT_BAR(N) do {                                              \
    asm volatile("s_waitcnt vmcnt(" #N ") lgkmcnt(0)" ::: "memory");       \
    __builtin_amdgcn_s_barrier();                                          \
    asm volatile("" ::: "memory");                                         \
} while (0)

__device__ __forceinline__ unsigned short f2bf(float f) {
    unsigned int x = __float_as_uint(f);
    unsigned int r = x + 0x7fffu + ((x >> 16) & 1u);   // RNE
    return (unsigned short)(r >> 16);
}

__device__ __forceinline__ unsigned int cvt_pk_bf16(float lo, float hi) {
    unsigned int r;
    asm("v_cvt_pk_bf16_f32 %0, %1, %2" : "=v"(r) : "v"(lo), "v"(hi));
    return r;
}

// raw v_exp_f32: computes 2^x. Q is pre-scaled by log2(e)/8, so softmax needs
// no per-element multiply (exp2-fold).
__device__ __forceinline__ float exp2_raw(float x) {
    float r;
    asm("v_exp_f32 %0, %1" : "=v"(r) : "v"(x));
    return r;
}

// async global->LDS, 16 B per lane. LDS dest = wave-uniform base + lane*16 (m104 caveat).
__device__ __forceinline__ void async16(const ushort_t* g, ushort_t* l) {
    __builtin_amdgcn_global_load_lds(
        (const __attribute__((address_space(1))) unsigned int*)g,
        (__attribute__((address_space(3))) unsigned int*)l,
        16, 0, 0);
}

// prep1 (1-D range decode): [0,6144) X cvt (z = bid>>11; q scaled by
// log2(e)/8 = 0.180336881 so flash softmax uses raw v_exp_f32);
// [6144,7680) W cvt (Wq/Wk/Wv fp32 -> bf16).
__global__ __launch_bounds__(256) void prep1(const float* __restrict__ q,
                                             const float* __restrict__ k,
                                             const float* __restrict__ v,
                                             const float* __restrict__ Wq,
                                             const float* __restrict__ Wk,
                                             const float* __restrict__ Wv,
                                             ushort_t* __restrict__ qb,
                                             ushort_t* __restrict__ kb,
                                             ushort_t* __restrict__ vb,
                                             ushort_t* __restrict__ Wqb,
                                             ushort_t* __restrict__ Wkb,
                                             ushort_t* __restrict__ Wvb) {
    const int bid = blockIdx.x;
    const int tid = threadIdx.x;
    const float* src; ushort_t* dst; float sc = 1.0f;
    if (bid < 6144) {
        const int z   = bid >> 11;
        const int blk = bid & 2047;
        const size_t idx = (((size_t)blk << 8) + tid) << 3;
        src = ((z == 0) ? q : (z == 1) ? k : v) + idx;
        dst = ((z == 0) ? qb : (z == 1) ? kb : vb) + idx;
        if (z == 0) sc = 0.18033688089f;   // log2(e)/8
    } else {
        const int qq   = bid - 6144;
        const int wsel = qq >> 9;
        const size_t idx = (((size_t)(qq & 511) << 8) + tid) << 3;
        src = ((wsel == 0) ? Wq : (wsel == 1) ? Wk : Wv) + idx;
        dst = ((wsel == 0) ? Wqb : (wsel == 1) ? Wkb : Wvb) + idx;
    }
    f32x4 a0 = *(const f32x4*)src, a1 = *(const f32x4*)(src + 4);
    ushort8 o;
    #pragma unroll
    for (int j = 0; j < 4; j++) { o[j] = f2bf(a0[j] * sc); o[j + 4] = f2bf(a1[j] * sc); }
    *(ushort8*)dst = o;
}

// prep2 (runs after gemm_proj; WoH/Mbits alias kb which is then dead):
// [0,4096) maskbits; [4096,5120) woswz.
__global__ __launch_bounds__(256) void prep2(const int* __restrict__ mask,
                                             const float* __restrict__ Wo,
                                             ushort_t* __restrict__ WoH,
                                             unsigned long long* __restrict__ Mbits) {
    __shared__ float srow[1024 + 64];
    const int bid = blockIdx.x;
    const int tid = threadIdx.x;
    if (bid < 4096) {
        const int row  = bid;
        const int w    = tid >> 6;
        const int lane = tid & 63;
        const int* mrow = mask + (size_t)row * 2048;
        #pragma unroll
        for (int it = 0; it < 8; it++) {
            const int o = (it << 8) + (w << 6) + lane;
            const unsigned long long bb = __ballot(mrow[o] != 0);
            if (lane == 0) Mbits[(size_t)((it << 2) + w) * 4096 + row] = bb;
        }
    } else {
        const int j = bid - 4096;
        f32x4 v = *(const f32x4*)(Wo + (size_t)j * 1024 + (tid << 2));
        #pragma unroll
        for (int s = 0; s < 4; s++) { const int c = (tid << 2) + s; srow[c + (c >> 4)] = v[s]; }
        __syncthreads();
        #pragma unroll
        for (int s = 0; s < 4; s++) {
            const int k = tid + (s << 8);
            const int col = ((k & 63) << 4) + (k >> 6);
            WoH[(size_t)j * 1024 + k] = f2bf(srow[col + (col >> 4)]);
        }
    }
}

// Fused QKV projection, 256x256 tile, BK=32, 512 threads (8 waves, wave-tile
// 128x64, acc 8x4), triple-buffered counted-vmcnt staging + 4-PHASE fine
// interleave (T3 analog of m201's 8-phase at BK=32): per phase
// {frag ds_reads for quadrant || 1 staging async16} -> s_barrier -> setprio(1)
// -> 8-MFMA cluster -> setprio(0) -> s_barrier. Mid-step barriers are
// alignment-only (reads target buf cur, staging writes buf nb); boundary keeps
// the verified vmcnt(4) invariant. Fragment-order LDS: 0 bank conflicts.
// Grid 192 (3z x 16m x 4n), the 4 n-blocks of (z,m) share one XCD.
// z=0: Qh[bh][l][d] (q pre-scaled log2e/8); z=1: Kh[bh][l][d]; z=2: VhT[bh][d][l].
__global__ __launch_bounds__(512, 2) void gemm_proj(const ushort_t* __restrict__ qb,
                                                    const ushort_t* __restrict__ kb,
                                                    const ushort_t* __restrict__ vb,
                                                    const ushort_t* __restrict__ Wqb,
                                                    const ushort_t* __restrict__ Wkb,
                                                    const ushort_t* __restrict__ Wvb,
                                                    ushort_t* __restrict__ Qh,
                                                    ushort_t* __restrict__ Kh,
                                                    ushort_t* __restrict__ VhT) {
    __shared__ ushort_t Xs[3][8192];   // 3 x 16 KB: [c4][256 rows][8]
    __shared__ ushort_t Ws[3][8192];   // 3 x 16 KB

    const int lid  = blockIdx.x;       // 0..191
    const int nIdx = lid / 48;         // 0..3
    const int rem  = lid % 48;
    const int z    = rem >> 4;         // 0..2
    const int mIdx = rem & 15;         // 0..15
    const int n0   = nIdx << 8;
    const int m0   = mIdx << 8;

    const ushort_t* Xb = (z == 0) ? qb : (z == 1) ? kb : vb;
    const ushort_t* Wb = (z == 0) ? Wqb : (z == 1) ? Wkb : Wvb;

    const int tid  = threadIdx.x;
    const int w    = tid >> 6;         // 0..7
    const int lane = tid & 63;
    const int lm   = lane & 15;
    const int quad = lane >> 4;
    const int wm   = w & 1;            // M half (128 rows)
    const int wn   = w >> 1;           // N quarter (64 cols)

    f32x4 acc[8][4];
    #pragma unroll
    for (int i = 0; i < 8; i++)
        #pragma unroll
        for (int j = 0; j < 4; j++) acc[i][j] = (f32x4){0.f, 0.f, 0.f, 0.f};

    // staging: 1024 lane-chunks of 16B cover [c4=4][256 rows]; wave w owns
    // chunks L = (w*2+i)*64 + lane, i<2. LDS index L*8 -> wave-uniform + lane*16.
    auto stageX1 = [&](int k0, int buf, int i) {
        const int L   = (((w << 1) + i) << 6) + lane;   // 0..1023
        const int c4  = L >> 8, row = L & 255;
        const int lb  = (((w << 1) + i) << 6) << 3;
        async16(Xb + (size_t)(m0 + row) * 1024 + k0 + (c4 << 3), &Xs[buf][lb]);
    };
    auto stageW1 = [&](int k0, int buf, int i) {
        const int L   = (((w << 1) + i) << 6) + lane;
        const int c4  = L >> 8, row = L & 255;
        const int lb  = (((w << 1) + i) << 6) << 3;
        async16(Wb + (size_t)(n0 + row) * 1024 + k0 + (c4 << 3), &Ws[buf][lb]);
    };
    auto stage = [&](int k0, int buf) {
        stageX1(k0, buf, 0); stageX1(k0, buf, 1);
        stageW1(k0, buf, 0); stageW1(k0, buf, 1);
    };

    stage(0, 0);                       // 4 loads/wave
    stage(32, 1);                      // +4 in flight
    PIPE_WAIT_BAR(4);                  // tile 0 ready; tile 1 flying

    int cur = 0;
    for (int t = 0; t < 32; ++t) {
        int nb = cur + 2; if (nb >= 3) nb -= 3;
        const bool pf  = (t < 30);
        const int  k0n = (t + 2) << 5;
        short8 af[4], bf[4];

        // ---- phase 0: af(mh=0) + bf(nh=0) reads || stage X.i0; MFMA (mh0,nh0)
        #pragma unroll
        for (int mf = 0; mf < 4; mf++)
            af[mf] = *(const short8*)&Xs[cur][((quad << 8) + (wm << 7) + (mf << 4) + lm) << 3];
        bf[0] = *(const short8*)&Ws[cur][((quad << 8) + (wn << 6) + (0 << 4) + lm) << 3];
        bf[1] = *(const short8*)&Ws[cur][((quad << 8) + (wn << 6) + (1 << 4) + lm) << 3];
        if (pf) stageX1(k0n, nb, 0);
        __builtin_amdgcn_s_barrier();
        __builtin_amdgcn_s_setprio(1);
        #pragma unroll
        for (int mf = 0; mf < 4; mf++) {
            acc[mf][0] = __builtin_amdgcn_mfma_f32_16x16x32_bf16(af[mf], bf[0], acc[mf][0], 0, 0, 0);
            acc[mf][1] = __builtin_amdgcn_mfma_f32_16x16x32_bf16(af[mf], bf[1], acc[mf][1], 0, 0, 0);
        }
        __builtin_amdgcn_s_setprio(0);
        __builtin_amdgcn_s_barrier();

        // ---- phase 1: bf(nh=1) reads || stage X.i1; MFMA (mh0,nh1)
        bf[2] = *(const short8*)&Ws[cur][((quad << 8) + (wn << 6) + (2 << 4) + lm) << 3];
        bf[3] = *(const short8*)&Ws[cur][((quad << 8) + (wn << 6) + (3 << 4) + lm) << 3];
        if (pf) stageX1(k0n, nb, 1);
        __builtin_amdgcn_s_barrier();
        __builtin_amdgcn_s_setprio(1);
        #pragma unroll
        for (int mf = 0; mf < 4; mf++) {
            acc[mf][2] = __builtin_amdgcn_mfma_f32_16x16x32_bf16(af[mf], bf[2], acc[mf][2], 0, 0, 0);
            acc[mf][3] = __builtin_amdgcn_mfma_f32_16x16x32_bf16(af[mf], bf[3], acc[mf][3], 0, 0, 0);
        }
        __builtin_amdgcn_s_setprio(0);
        __builtin_amdgcn_s_barrier();

        // ---- phase 2: af(mh=1) reads || stage W.i0; MFMA (mh1,nh0)
        #pragma unroll
        for (int mf = 0; mf < 4; mf++)
            af[mf] = *(const short8*)&Xs[cur][((quad << 8) + (wm << 7) + 64 + (mf << 4) + lm) << 3];
        if (pf) stageW1(k0n, nb, 0);
        __builtin_amdgcn_s_barrier();
        __builtin_amdgcn_s_setprio(1);
        #pragma unroll
        for (int mf = 0; mf < 4; mf++) {
            acc[4 + mf][0] = __builtin_amdgcn_mfma_f32_16x16x32_bf16(af[mf], bf[0], acc[4 + mf][0], 0, 0, 0);
            acc[4 + mf][1] = __builtin_amdgcn_mfma_f32_16x16x32_bf16(af[mf], bf[1], acc[4 + mf][1], 0, 0, 0);
        }
        __builtin_amdgcn_s_setprio(0);
        __builtin_amdgcn_s_barrier();

        // ---- phase 3: stage W.i1; MFMA (mh1,nh1); boundary counted-vmcnt bar
        if (pf) stageW1(k0n, nb, 1);
        __builtin_amdgcn_s_setprio(1);
        #pragma unroll
        for (int mf = 0; mf < 4; mf++) {
            acc[4 + mf][2] = __builtin_amdgcn_mfma_f32_16x16x32_bf16(af[mf], bf[2], acc[4 + mf][2], 0, 0, 0);
            acc[4 + mf][3] = __builtin_amdgcn_mfma_f32_16x16x32_bf16(af[mf], bf[3], acc[4 + mf][3], 0, 0, 0);
        }
        __builtin_amdgcn_s_setprio(0);
        if (t < 30)       PIPE_WAIT_BAR(4);   // t+1 done; t+2 in flight
        else if (t == 30) PIPE_WAIT_BAR(0);   // last tile: drain
        cur += 1; if (cur == 3) cur = 0;
    }

    // Direct stores. col = n0 + wn*64 + nf*16 + lm -> h = lm, d = 16*nIdx + 4*wn + nf.
    const int bb    = m0 >> 11;
    const int l0    = m0 & 2047;
    const int dbase = (n0 >> 4) + (wn << 2);
    if (z != 2) {
        ushort_t* OUT = (z == 0) ? Qh : Kh;
        #pragma unroll
        for (int mf = 0; mf < 8; mf++)
            #pragma unroll
            for (int r = 0; r < 4; r++) {
                const int row = (wm << 7) + (mf << 4) + (quad << 2) + r;
                ushort4v o = { f2bf(acc[mf][0][r]), f2bf(acc[mf][1][r]),
                               f2bf(acc[mf][2][r]), f2bf(acc[mf][3][r]) };
                *(ushort4v*)(OUT + ((size_t)((bb << 4) + lm) * 2048 + l0 + row) * 64 + dbase) = o;
            }
    } else {
        #pragma unroll
        for (int mf = 0; mf < 8; mf++)
            #pragma unroll
            for (int nf = 0; nf < 4; nf++) {
                const int lbase = l0 + (wm << 7) + (mf << 4) + (quad << 2);
                ushort4v o = { f2bf(acc[mf][nf][0]), f2bf(acc[mf][nf][1]),
                               f2bf(acc[mf][nf][2]), f2bf(acc[mf][nf][3]) };
                *(ushort4v*)(VhT + ((size_t)((bb << 4) + lm) * 64 + dbase + nf) * 2048 + lbase) = o;
            }
    }
}

// Output GEMM, 128x64 tile, BK=32, triple-buffered counted-vmcnt staging
// (3 loads/wave/step -> vmcnt(3)), 512 blocks. XCD-grouped m-panels.
__global__ __launch_bounds__(256) void gemm_out(const ushort_t* __restrict__ mhaH,
                                                const ushort_t* __restrict__ WoH,
                                                float* __restrict__ C) {
    __shared__ ushort_t Xs[3][4096];   // [c4][128 rows][8] 3 x 8KB
    __shared__ ushort_t Ws[3][2048];   // [c4][64 rows][8] 3 x 4KB

    const int lid  = blockIdx.x;       // 0..511
    const int mIdx = ((lid & 7) << 2) | ((lid >> 3) & 3);   // 0..31
    const int nIdx = lid >> 5;                               // 0..15
    const int m0   = mIdx << 7;
    const int n0   = nIdx << 6;

    const int tid  = threadIdx.x;
    const int w    = tid >> 6;
    const int lane = tid & 63;
    const int lm   = lane & 15;
    const int quad = lane >> 4;
    const int wm   = w & 1;            // M half (64 rows)
    const int wn   = w >> 1;           // N half (32 cols)
    const int ab   = m0 >> 11;
    const int al0  = m0 & 2047;

    f32x4 acc[4][2];
    #pragma unroll
    for (int i = 0; i < 4; i++)
        #pragma unroll
        for (int j = 0; j < 2; j++) acc[i][j] = (f32x4){0.f, 0.f, 0.f, 0.f};

    auto stage = [&](int k0, int buf) {
        const int h  = k0 >> 6;
        const int d0 = k0 & 63;
        #pragma unroll
        for (int i = 0; i < 2; i++) {
            const int L   = (i << 8) + (w << 6) + lane;     // 0..511
            const int c4  = L >> 7, row = L & 127;
            async16(mhaH + ((size_t)(ab * 16 + h) * 2048 + al0 + row) * 64 + d0 + (c4 << 3),
                    &Xs[buf][((i << 8) + (w << 6)) << 3]);
        }
        {
            const int L   = (w << 6) + lane;                // 0..255
            const int c4  = L >> 6, row = L & 63;
            async16(WoH + (size_t)(n0 + row) * 1024 + k0 + (c4 << 3),
                    &Ws[buf][(w << 6) << 3]);
        }
    };

    stage(0, 0);
    stage(32, 1);
    PIPE_WAIT_BAR(3);

    int cur = 0;
    for (int t = 0; t < 32; ++t) {
        int nb = cur + 2; if (nb >= 3) nb -= 3;
        if (t < 30) stage((t + 2) << 5, nb);
        short8 af[4], bf2[2];
        #pragma unroll
        for (int mf = 0; mf < 4; mf++)
            af[mf] = *(const short8*)&Xs[cur][((quad << 7) + (wm << 6) + (mf << 4) + lm) << 3];
        #pragma unroll
        for (int nf = 0; nf < 2; nf++)
            bf2[nf] = *(const short8*)&Ws[cur][((quad << 6) + (wn << 5) + (nf << 4) + lm) << 3];
        #pragma unroll
        for (int mf = 0; mf < 4; mf++)
            #pragma unroll
            for (int nf = 0; nf < 2; nf++)
                acc[mf][nf] = __builtin_amdgcn_mfma_f32_16x16x32_bf16(af[mf], bf2[nf], acc[mf][nf], 0, 0, 0);
        if (t < 30)       PIPE_WAIT_BAR(3);
        else if (t == 30) PIPE_WAIT_BAR(0);
        cur += 1; if (cur == 3) cur = 0;
    }
    #pragma unroll
    for (int mf = 0; mf < 4; mf++)
        #pragma unroll
        for (int nf = 0; nf < 2; nf++)
            #pragma unroll
            for (int r = 0; r < 4; r++) {
                const int row = m0 + (wm << 6) + (mf << 4) + (quad << 2) + r;
                const int col = n0 + (wn << 5) + (nf << 4) + lm;
                C[(size_t)row * 1024 + col] = acc[mf][nf][r];
            }
}

// MFMA flash attention v8: v7 + (a) exp2-fold — Q pre-scaled by log2(e)/8 so
// softmax is raw v_exp_f32, no per-element multiply; (b) MFMA l-sum — row sums
// via 2 extra MFMAs/g against an all-ones B fragment (D[m][n]=sum_k P[m][k]),
// replacing 32 VALU adds/tile and the epilogue shfl reduction; every lane gets
// its rows' full sums in the C layout directly. Denominator now uses the same
// bf16 P as the PV numerator (consistent weighted average).
// Grid 512 1-D, XCD-grouped bh (K+V+Q+mask ~3.5MB per XCD L2).
__global__ __launch_bounds__(256, 2) void flash_attn(const ushort_t* __restrict__ Qh,
                                                     const ushort_t* __restrict__ Kh,
                                                     const ushort_t* __restrict__ VhT,
                                                     const unsigned long long* __restrict__ Mbits,
                                                     ushort_t* __restrict__ mhaH) {
    __shared__ ushort_t Ks[3][4096];            // 3 x 8KB fragment-order K tile
    __shared__ ushort_t Vs[3][4096];            // 3 x 8KB fragment-order V^T tile
    __shared__ ushort_t Pw[4][2][16 * LPAD];    // per-wave per-g P [qrow16][key64]

    const int tid  = threadIdx.x;
    const int w    = tid >> 6;
    const int lane = tid & 63;
    const int lm   = lane & 15;
    const int quad = lane >> 4;
    const int lid  = blockIdx.x;             // 0..511
    const int bh   = ((lid & 7) << 2) | ((lid >> 3) & 3);   // 0..31, XCD-grouped
    const int q0   = (lid >> 5) << 7;        // 0..1920
    const int b    = bh >> 4;

    const ushort_t* Qb  = Qh  + ((size_t)bh << 17);
    const ushort_t* Kb  = Kh  + ((size_t)bh << 17);
    const ushort_t* Vtb = VhT + ((size_t)bh << 17);   // [d][l]

    short8 aq[2][2];
    #pragma unroll
    for (int g = 0; g < 2; g++) {
        const ushort_t* qp = Qb + (size_t)(q0 + (w << 5) + (g << 4) + lm) * 64 + (quad << 3);
        aq[g][0] = *(const short8*)qp;
        aq[g][1] = *(const short8*)(qp + 32);
    }

    // all-ones bf16 B fragment for the l-sum MFMA (bf16 1.0 = 0x3F80)
    short8 bones;
    #pragma unroll
    for (int j = 0; j < 8; j++) bones[j] = (short)0x3F80;

    f32x4 l_acc[2] = {{0.f,0.f,0.f,0.f},{0.f,0.f,0.f,0.f}};
    f32x4 o_acc[2][4] = {{{0.f,0.f,0.f,0.f},{0.f,0.f,0.f,0.f},{0.f,0.f,0.f,0.f},{0.f,0.f,0.f,0.f}},
                         {{0.f,0.f,0.f,0.f},{0.f,0.f,0.f,0.f},{0.f,0.f,0.f,0.f},{0.f,0.f,0.f,0.f}}};

    const int rowbase  = (b << 11) + q0 + (w << 5);
    const int shamt    = (lm & 7) << 2;
    const bool hi_half = lm >= 8;

    const ushort_t* ksrc = Kb  + (size_t)((lm << 2) + w) * 64 + (quad << 3);
    const ushort_t* vsrc = Vtb + (size_t)((w << 4) + lm) * 2048 + (quad << 3);

    auto stageKV = [&](int kt0, int buf) {
        async16(ksrc + (size_t)kt0 * 64,      &Ks[buf][((w << 7)     ) << 3]);
        async16(ksrc + (size_t)kt0 * 64 + 32, &Ks[buf][((w << 7) + 64) << 3]);
        async16(vsrc + kt0,      &Vs[buf][((w << 7)     ) << 3]);
        async16(vsrc + kt0 + 32, &Vs[buf][((w << 7) + 64) << 3]);
    };

    stageKV(0, 0);
    stageKV(64, 1);
    PIPE_WAIT_BAR(4);

    int cur = 0;
    for (int t = 0; t < 32; ++t) {
        const int kt0 = t << 6;
        int nb = cur + 2; if (nb >= 3) nb -= 3;

        // mask words FIRST (older than stage loads -> their auto-wait leaves
        // the prefetch in flight)
        const unsigned long long* Mt = Mbits + (size_t)(kt0 >> 6) * 4096 + rowbase;
        unsigned long long mb[2][4];
        #pragma unroll
        for (int g = 0; g < 2; g++) {
            const unsigned long long* mp = Mt + (g << 4) + (quad << 2);
            ull2 t0 = *(const ull2*)mp;
            ull2 t1 = *(const ull2*)(mp + 2);
            mb[g][0] = t0[0]; mb[g][1] = t0[1]; mb[g][2] = t1[0]; mb[g][3] = t1[1];
        }

        if (t < 30) stageKV(kt0 + 128, nb);   // depth-2 prefetch

        // fragment reads: lane-linear, conflict-free
        short8 bk[4][2], bv[4][2];
        #pragma unroll
        for (int c = 0; c < 4; c++) {
            bk[c][0] = *(const short8*)&Ks[cur][((c << 7) + lane) << 3];
            bk[c][1] = *(const short8*)&Ks[cur][((c << 7) + 64 + lane) << 3];
            bv[c][0] = *(const short8*)&Vs[cur][((c << 7) + lane) << 3];
            bv[c][1] = *(const short8*)&Vs[cur][((c << 7) + 64 + lane) << 3];
        }

        // QK^T both g (S col lm of block c <-> key 4*lm + c); s = qk * log2e/8
        f32x4 s[2][4];
        __builtin_amdgcn_s_setprio(1);
        #pragma unroll
        for (int g = 0; g < 2; g++)
            #pragma unroll
            for (int c = 0; c < 4; c++) {
                f32x4 zz = {0.f, 0.f, 0.f, 0.f};
                zz = __builtin_amdgcn_mfma_f32_16x16x32_bf16(aq[g][0], bk[c][0], zz, 0, 0, 0);
                zz = __builtin_amdgcn_mfma_f32_16x16x32_bf16(aq[g][1], bk[c][1], zz, 0, 0, 0);
                s[g][c] = zz;
            }
        __builtin_amdgcn_s_setprio(0);

        // softmax (raw 2^x) + packed P-write, g0 then g1 (independent buffers)
        #pragma unroll
        for (int g = 0; g < 2; g++) {
            #pragma unroll
            for (int r = 0; r < 4; r++) {
                const unsigned long long m64 = mb[g][r];
                const unsigned word = hi_half ? (unsigned)(m64 >> 32) : (unsigned)m64;
                const unsigned nib  = (word >> shamt) & 0xFu;   // bits for keys 4lm..4lm+3
                float p0 = exp2_raw(s[g][0][r]); if (nib & 1u) p0 = 0.f;
                float p1 = exp2_raw(s[g][1][r]); if (nib & 2u) p1 = 0.f;
                float p2 = exp2_raw(s[g][2][r]); if (nib & 4u) p2 = 0.f;
                float p3 = exp2_raw(s[g][3][r]); if (nib & 8u) p3 = 0.f;
                uint2v pv2;
                pv2[0] = cvt_pk_bf16(p0, p1);
                pv2[1] = cvt_pk_bf16(p2, p3);
                *(uint2v*)&Pw[w][g][((quad << 2) + r) * LPAD + (lm << 2)] = pv2;
            }
        }

        // P reads + PV + l-sum MFMA, g0 then g1
        __builtin_amdgcn_s_setprio(1);
        #pragma unroll
        for (int g = 0; g < 2; g++) {
            short8 ap0 = *(const short8*)&Pw[w][g][lm * LPAD + (quad << 3)];
            short8 ap1 = *(const short8*)&Pw[w][g][lm * LPAD + 32 + (quad << 3)];
            #pragma unroll
            for (int cd = 0; cd < 4; cd++) {
                o_acc[g][cd] = __builtin_amdgcn_mfma_f32_16x16x32_bf16(ap0, bv[cd][0], o_acc[g][cd], 0, 0, 0);
                o_acc[g][cd] = __builtin_amdgcn_mfma_f32_16x16x32_bf16(ap1, bv[cd][1], o_acc[g][cd], 0, 0, 0);
            }
            l_acc[g] = __builtin_amdgcn_mfma_f32_16x16x32_bf16(ap0, bones, l_acc[g], 0, 0, 0);
            l_acc[g] = __builtin_amdgcn_mfma_f32_16x16x32_bf16(ap1, bones, l_acc[g], 0, 0, 0);
        }
        __builtin_amdgcn_s_setprio(0);

        if (t < 30)       PIPE_WAIT_BAR(4);   // t+1 staged; t+2 in flight
        else if (t == 30) PIPE_WAIT_BAR(0);
        cur += 1; if (cur == 3) cur = 0;
    }

    // epilogue: l_acc[g][r] already holds the FULL row sum (all cols equal) --
    // no cross-lane reduction needed.
    #pragma unroll
    for (int g = 0; g < 2; g++) {
        #pragma unroll
        for (int r = 0; r < 4; r++) {
            const float inv_l = 1.0f / l_acc[g][r];
            const int i = q0 + (w << 5) + (g << 4) + (quad << 2) + r;
            ushort_t* orow = mhaH + (((size_t)bh * 2048 + i) << 6);
            #pragma unroll
            for (int cd = 0; cd < 4; cd++)
                orow[(cd << 4) + lm] = f2bf(o_acc[g][cd][r] * inv_l);
        }
    }
}

extern "C" void kernel_launch(void* const* d_in, const int* in_sizes, int n_in,
                              void* d_out, int out_size, void* d_ws, size_t ws_size,
                              hipStream_t stream) {
    const float* q    = (const float*)d_in[0];
    const float* k    = (const float*)d_in[1];
    const float* v    = (const float*)d_in[2];
    const int*   mask = (const int*)d_in[3];
    const float* Wq   = (const float*)d_in[4];
    const float* Wk   = (const float*)d_in[5];
    const float* Wv   = (const float*)d_in[6];
    const float* Wo   = (const float*)d_in[7];
    float* out = (float*)d_out;

    // ws plan (u16 units): qb kb vb (4M) | Wqb Wkb Wvb (1M) | Qh Kh VhT (4M) = 27M u16 = 54 MB
    // mhaH aliases qb; WoH + Mbits alias kb (both dead after gemm_proj; prep2
    // writes them AFTER gemm_proj).
    ushort_t* qb   = (ushort_t*)d_ws;
    ushort_t* kb   = qb  + 4194304;
    ushort_t* vb   = kb  + 4194304;
    ushort_t* Wqb  = vb  + 4194304;
    ushort_t* Wkb  = Wqb + 1048576;
    ushort_t* Wvb  = Wkb + 1048576;
    ushort_t* Qh   = Wvb + 1048576;
    ushort_t* Kh   = Qh  + 4194304;
    ushort_t* VhT  = Kh  + 4194304;
    ushort_t* mhaH = qb;
    ushort_t* WoH  = kb;
    unsigned long long* Mbits = (unsigned long long*)(kb + 1048576);

    dim3 gb(256);
    prep1<<<dim3(7680), gb, 0, stream>>>(q, k, v, Wq, Wk, Wv, qb, kb, vb, Wqb, Wkb, Wvb);
    gemm_proj<<<dim3(192), dim3(512), 0, stream>>>(qb, kb, vb, Wqb, Wkb, Wvb, Qh, Kh, VhT);
    prep2<<<dim3(5120), gb, 0, stream>>>(mask, Wo, WoH, Mbits);
    flash_attn<<<dim3(512), gb, 0, stream>>>(Qh, Kh, VhT, Mbits, mhaH);
    gemm_out<<<dim3(512), gb, 0, stream>>>(mhaH, WoH, out);
}